// Round 5
// baseline (4989.854 us; speedup 1.0000x reference)
//
#include <hip/hip_runtime.h>
#include <hip/hip_bf16.h>

static constexpr int TG_NN = 100000;
static constexpr int TG_NE = 1200000;
static constexpr int TG_D  = 64;
static constexpr int TG_NC = 40;
static constexpr int TG_BT = 256;
static constexpr int TG_NP = (TG_NN + 1023) / 1024;  // scan blocks (98)

// ---- dtype-flexible load/store (isF32: 1 = fp32 storage, 0 = bf16) ----
__device__ __forceinline__ float tg71_ld(const void* p, long i, int isF32) {
    if (isF32) return ((const float*)p)[i];
    return __uint_as_float(((unsigned int)((const unsigned short*)p)[i]) << 16);
}
__device__ __forceinline__ void tg71_st(void* p, long i, int isF32, float v) {
    if (isF32) ((float*)p)[i] = v;
    else ((__hip_bfloat16*)p)[i] = __float2bfloat16(v);
}
// 4-wide load (i multiple of 4)
__device__ __forceinline__ float4 tg71_ld4(const void* p, long i, int isF32) {
    if (isF32) return *(const float4*)((const float*)p + i);
    ushort4 u = *(const ushort4*)((const unsigned short*)p + i);
    float4 r;
    r.x = __uint_as_float(((unsigned int)u.x) << 16);
    r.y = __uint_as_float(((unsigned int)u.y) << 16);
    r.z = __uint_as_float(((unsigned int)u.z) << 16);
    r.w = __uint_as_float(((unsigned int)u.w) << 16);
    return r;
}

// flags[0] = edge_index is int64 ; flags[1] = float tensors are fp32
__global__ void tg71_detect(const int* ei, const unsigned short* w1bits, int* flags) {
    if (threadIdx.x == 0 && blockIdx.x == 0) {
        int i64 = 1;
        for (int k = 0; k < 64; ++k)
            if (ei[2 * k + 1] != 0) { i64 = 0; break; }
        flags[0] = i64;
        int f32 = 0;
        for (int k = 0; k < 2048; ++k) {
            float v = __uint_as_float(((unsigned int)w1bits[k]) << 16);
            if (!(v == v) || fabsf(v) > 1e4f) { f32 = 1; break; }
        }
        flags[1] = f32;
    }
}

// Sentinel fill (diagnostic; overwritten by the fused head in tg71_gemm_tiled).
extern "C" __global__ void TAGModel_71227737636876_kernel(void* out, const int* flags) {
    long i = (long)blockIdx.x * blockDim.x + threadIdx.x;
    if (i < (long)TG_NN * TG_NC) tg71_st(out, i, flags[1], 123.0f);
}

__global__ void tg71_edges(const int* ei, const int* flags, int* srcI, int* dstI) {
    int e = blockIdx.x * blockDim.x + threadIdx.x;
    if (e >= TG_NE) return;
    if (flags[0]) { srcI[e] = ei[2 * e]; dstI[e] = ei[2 * TG_NE + 2 * e]; }
    else          { srcI[e] = ei[e];     dstI[e] = ei[TG_NE + e]; }
}

__global__ void tg71_zero_i(int* p, int n) {
    int i = blockIdx.x * blockDim.x + threadIdx.x;
    if (i < n) p[i] = 0;
}

__global__ void tg71_hist(const int* dstI, int* cnt) {
    int e = blockIdx.x * blockDim.x + threadIdx.x;
    if (e < TG_NE) atomicAdd(cnt + dstI[e], 1);
}

__global__ void tg71_dis(const int* cnt, float* dis) {
    int i = blockIdx.x * blockDim.x + threadIdx.x;
    if (i < TG_NN) { int c = cnt[i]; dis[i] = c > 0 ? rsqrtf((float)c) : 0.0f; }
}

// ---- hierarchical exclusive scan of cnt[NN] -> rowptr[NN+1] ----
__global__ void tg71_scan1(const int* cnt, int* rowptr, int* part) {
    __shared__ int sh[256];
    int t = threadIdx.x;
    int base = blockIdx.x * 1024 + t * 4;
    int v0 = base + 0 < TG_NN ? cnt[base + 0] : 0;
    int v1 = base + 1 < TG_NN ? cnt[base + 1] : 0;
    int v2 = base + 2 < TG_NN ? cnt[base + 2] : 0;
    int v3 = base + 3 < TG_NN ? cnt[base + 3] : 0;
    int p1 = v0, p2 = v0 + v1, p3 = v0 + v1 + v2, sum = p3 + v3;
    sh[t] = sum;
    __syncthreads();
    for (int off = 1; off < 256; off <<= 1) {
        int x = (t >= off) ? sh[t - off] : 0;
        __syncthreads();
        if (t >= off) sh[t] += x;
        __syncthreads();
    }
    int ex = sh[t] - sum;
    if (base + 0 < TG_NN) rowptr[base + 0] = ex;
    if (base + 1 < TG_NN) rowptr[base + 1] = ex + p1;
    if (base + 2 < TG_NN) rowptr[base + 2] = ex + p2;
    if (base + 3 < TG_NN) rowptr[base + 3] = ex + p3;
    if (t == 255) part[blockIdx.x] = sh[255];
}

__global__ void tg71_scan2(int* part) {
    __shared__ int sh[128];
    int t = threadIdx.x;
    int v = t < TG_NP ? part[t] : 0;
    sh[t] = v;
    __syncthreads();
    for (int off = 1; off < 128; off <<= 1) {
        int x = (t >= off) ? sh[t - off] : 0;
        __syncthreads();
        if (t >= off) sh[t] += x;
        __syncthreads();
    }
    if (t < TG_NP) part[t] = sh[t] - v;
}

__global__ void tg71_scan3(int* rowptr, const int* part, int* fill) {
    int i = blockIdx.x * blockDim.x + threadIdx.x;
    if (i < TG_NN) {
        int r = rowptr[i] + part[i >> 10];
        rowptr[i] = r;
        fill[i] = r;
    }
    if (i == 0) rowptr[TG_NN] = TG_NE;
}

__global__ void tg71_scatter(const int* srcI, const int* dstI, int* fill, int* srcS) {
    int e = blockIdx.x * blockDim.x + threadIdx.x;
    if (e >= TG_NE) return;
    int pos = atomicAdd(fill + dstI[e], 1);
    srcS[pos] = srcI[e];
}

// ---- propagation in scaled space: g'[n] = (1/deg[n]) * sum_{src->n} g[src] ----

__global__ void tg71_prop_first(const int* rowptr, const int* srcS, const int* cnt,
                                const float* dis, const void* h, const int* flags,
                                int mode, float* out) {
    int gid = blockIdx.x * blockDim.x + threadIdx.x;
    int n = gid >> 6, lane = gid & 63;
    int isF32 = mode ? 1 : flags[1];
    int r0 = rowptr[n], r1 = rowptr[n + 1];
    float acc = 0.0f;
    int k = r0;
    for (; k + 4 <= r1; k += 4) {
        int s0 = srcS[k], s1 = srcS[k + 1], s2 = srcS[k + 2], s3 = srcS[k + 3];
        float d0 = dis[s0], d1 = dis[s1], d2 = dis[s2], d3 = dis[s3];
        float a0 = tg71_ld(h, (long)s0 * TG_D + lane, isF32) * d0;
        float a1 = tg71_ld(h, (long)s1 * TG_D + lane, isF32) * d1;
        float a2 = tg71_ld(h, (long)s2 * TG_D + lane, isF32) * d2;
        float a3 = tg71_ld(h, (long)s3 * TG_D + lane, isF32) * d3;
        acc += (a0 + a1) + (a2 + a3);
    }
    for (; k < r1; ++k) {
        int s = srcS[k];
        acc += tg71_ld(h, (long)s * TG_D + lane, isF32) * dis[s];
    }
    int c = cnt[n];
    float inv = c > 0 ? 1.0f / (float)c : 0.0f;
    out[(long)n * TG_D + lane] = acc * inv;
}

__global__ void tg71_prop(const int* rowptr, const int* srcS, const int* cnt,
                          const float* g, float* out) {
    int gid = blockIdx.x * blockDim.x + threadIdx.x;
    int n = gid >> 6, lane = gid & 63;
    int r0 = rowptr[n], r1 = rowptr[n + 1];
    float acc = 0.0f;
    int k = r0;
    for (; k + 4 <= r1; k += 4) {
        int s0 = srcS[k], s1 = srcS[k + 1], s2 = srcS[k + 2], s3 = srcS[k + 3];
        float a0 = g[(long)s0 * TG_D + lane];
        float a1 = g[(long)s1 * TG_D + lane];
        float a2 = g[(long)s2 * TG_D + lane];
        float a3 = g[(long)s3 * TG_D + lane];
        acc += (a0 + a1) + (a2 + a3);
    }
    for (; k < r1; ++k) acc += g[(long)srcS[k] * TG_D + lane];
    int c = cnt[n];
    float inv = c > 0 ? 1.0f / (float)c : 0.0f;
    out[(long)n * TG_D + lane] = acc * inv;
}

// ---- tiled GEMM helpers ----

// stage W rows [seg*64, seg*64+64) into sW (fp32)
__device__ __forceinline__ void tg71_stageW(const void* W, int fF, int seg, int t,
                                            float (&sW)[64][64]) {
    for (int i = t; i < 64 * 64; i += 256)
        sW[i >> 6][i & 63] = tg71_ld(W, (long)seg * 64 * 64 + i, fF);
}

// accumulate one K-segment: acc{0,1}[q] += h{n0,n1}[f] * sW[f][j0+q]
__device__ __forceinline__ void tg71_seg(const void* hp, int hf, long n0, long n1,
                                         bool v0, bool v1, int j0,
                                         const float (&sW)[64][64],
                                         float (&a0)[8], float (&a1)[8]) {
    for (int f = 0; f < 64; f += 4) {
        float4 h0v = v0 ? tg71_ld4(hp, n0 * TG_D + f, hf) : float4{0, 0, 0, 0};
        float4 h1v = v1 ? tg71_ld4(hp, n1 * TG_D + f, hf) : float4{0, 0, 0, 0};
#pragma unroll
        for (int ff = 0; ff < 4; ++ff) {
            float w[8];
            *(float4*)&w[0] = *(const float4*)&sW[f + ff][j0];
            *(float4*)&w[4] = *(const float4*)&sW[f + ff][j0 + 4];
            float h0s = ff == 0 ? h0v.x : (ff == 1 ? h0v.y : (ff == 2 ? h0v.z : h0v.w));
            float h1s = ff == 0 ? h1v.x : (ff == 1 ? h1v.y : (ff == 2 ? h1v.z : h1v.w));
#pragma unroll
            for (int q = 0; q < 8; ++q) {
                a0[q] += h0s * w[q];
                a1[q] += h1s * w[q];
            }
        }
    }
}

// y = relu(b + h0@W[0:64] + s*(g1@W[64:128]+g2@W[128:192]+g3@W[192:256]))
// doHead: also compute out = z@Wc + bc (z stays in LDS)
__global__ __launch_bounds__(256) void tg71_gemm_tiled(
    const void* h0, int h0IsF32, const float* g1, const float* g2, const float* g3,
    const void* W, const void* bias, const int* cnt, const int* flags,
    float* yOut, int doHead, const void* Wc, const void* bc, void* outp) {
    __shared__ float sW[64][64];   // 16 KB: one W K-segment
    __shared__ float sZ[64][68];   // 17.4 KB: z staging for fused head

    const int t = threadIdx.x;
    const int jb = t & 7;          // 0..7
    const int mp = t >> 3;         // 0..31
    const int j0 = jb * 8;
    const int fF = flags[1];
    const int h0f = h0IsF32 ? 1 : fF;
    const long tile = (long)blockIdx.x * 64;
    const long n0 = tile + mp, n1 = tile + mp + 32;
    const bool v0 = n0 < TG_NN, v1 = n1 < TG_NN;

    float aA0[8], aA1[8], aG0[8], aG1[8];
#pragma unroll
    for (int q = 0; q < 8; ++q) { aA0[q] = aA1[q] = aG0[q] = aG1[q] = 0.0f; }

    tg71_stageW(W, fF, 0, t, sW);
    __syncthreads();
    tg71_seg(h0, h0f, n0, n1, v0, v1, j0, sW, aA0, aA1);
    __syncthreads();
    tg71_stageW(W, fF, 1, t, sW);
    __syncthreads();
    tg71_seg(g1, 1, n0, n1, v0, v1, j0, sW, aG0, aG1);
    __syncthreads();
    tg71_stageW(W, fF, 2, t, sW);
    __syncthreads();
    tg71_seg(g2, 1, n0, n1, v0, v1, j0, sW, aG0, aG1);
    __syncthreads();
    tg71_stageW(W, fF, 3, t, sW);
    __syncthreads();
    tg71_seg(g3, 1, n0, n1, v0, v1, j0, sW, aG0, aG1);

    int c0 = v0 ? cnt[n0] : 0;
    int c1 = v1 ? cnt[n1] : 0;
    float s0 = c0 > 0 ? sqrtf((float)c0) : 0.0f;
    float s1 = c1 > 0 ? sqrtf((float)c1) : 0.0f;
    float z0[8], z1[8];
#pragma unroll
    for (int q = 0; q < 8; ++q) {
        float b = tg71_ld(bias, j0 + q, fF);
        z0[q] = fmaxf(b + aA0[q] + s0 * aG0[q], 0.0f);
        z1[q] = fmaxf(b + aA1[q] + s1 * aG1[q], 0.0f);
    }

    if (!doHead) {
        if (v0) {
            *(float4*)&yOut[n0 * TG_D + j0]     = *(float4*)&z0[0];
            *(float4*)&yOut[n0 * TG_D + j0 + 4] = *(float4*)&z0[4];
        }
        if (v1) {
            *(float4*)&yOut[n1 * TG_D + j0]     = *(float4*)&z1[0];
            *(float4*)&yOut[n1 * TG_D + j0 + 4] = *(float4*)&z1[4];
        }
        return;
    }

    // fused head: stage z, then out[n][c] = bc[c] + z[n,:]·Wc[:,c]
    *(float4*)&sZ[mp][j0]          = *(float4*)&z0[0];
    *(float4*)&sZ[mp][j0 + 4]      = *(float4*)&z0[4];
    *(float4*)&sZ[mp + 32][j0]     = *(float4*)&z1[0];
    *(float4*)&sZ[mp + 32][j0 + 4] = *(float4*)&z1[4];
    __syncthreads();
    for (int idx = t; idx < 64 * TG_NC; idx += 256) {
        int mm = idx / TG_NC, c = idx - mm * TG_NC;
        long n = tile + mm;
        if (n < TG_NN) {
            float acc = tg71_ld(bc, c, fF);
#pragma unroll 8
            for (int f = 0; f < TG_D; ++f)
                acc += sZ[mm][f] * tg71_ld(Wc, (long)f * TG_NC + c, fF);
            tg71_st(outp, n * TG_NC + c, fF, acc);
        }
    }
}

extern "C" void kernel_launch(void* const* d_in, const int* in_sizes, int n_in,
                              void* d_out, int out_size, void* d_ws, size_t ws_size,
                              hipStream_t stream) {
    const void* x  = d_in[0];
    const int*  ei = (const int*)d_in[1];
    const void* W1 = d_in[2];
    const void* b1 = d_in[3];
    const void* W2 = d_in[4];
    const void* b2 = d_in[5];
    const void* Wc = d_in[6];
    const void* bc = d_in[7];

    // workspace layout (4-byte words) ~119 MB
    int*   flags  = (int*)d_ws;                     // [16]
    int*   srcI   = flags + 16;                     // [NE]
    int*   dstI   = srcI + TG_NE;                   // [NE]
    int*   srcS   = dstI + TG_NE;                   // [NE]
    int*   cnt    = srcS + TG_NE;                   // [NN]
    float* dis    = (float*)(cnt + TG_NN);          // [NN]
    int*   rowptr = (int*)(dis + TG_NN);            // [NN+1]
    int*   fill   = rowptr + TG_NN + 1;             // [NN]
    int*   part   = fill + TG_NN;                   // [128]
    float* A      = (float*)(part + 128);           // [NN*D]
    float* B      = A + (long)TG_NN * TG_D;         // [NN*D]
    float* C      = B + (long)TG_NN * TG_D;         // [NN*D]
    float* Y      = C + (long)TG_NN * TG_D;         // [NN*D]

    const int gE  = (TG_NE + TG_BT - 1) / TG_BT;
    const int gN  = (TG_NN + TG_BT - 1) / TG_BT;
    const int gP  = TG_NN * TG_D / TG_BT;           // 25000
    const int gNC = (TG_NN * TG_NC + TG_BT - 1) / TG_BT;
    const int gT  = (TG_NN + 63) / 64;              // 1563 gemm tiles

    tg71_detect<<<1, 64, 0, stream>>>(ei, (const unsigned short*)W1, flags);
    TAGModel_71227737636876_kernel<<<gNC, TG_BT, 0, stream>>>(d_out, flags);

    // CSR build
    tg71_edges<<<gE, TG_BT, 0, stream>>>(ei, flags, srcI, dstI);
    tg71_zero_i<<<gN, TG_BT, 0, stream>>>(cnt, TG_NN);
    tg71_hist<<<gE, TG_BT, 0, stream>>>(dstI, cnt);
    tg71_dis<<<gN, TG_BT, 0, stream>>>(cnt, dis);
    tg71_scan1<<<TG_NP, TG_BT, 0, stream>>>(cnt, rowptr, part);
    tg71_scan2<<<1, 128, 0, stream>>>(part);
    tg71_scan3<<<gN, TG_BT, 0, stream>>>(rowptr, part, fill);
    tg71_scatter<<<gE, TG_BT, 0, stream>>>(srcI, dstI, fill, srcS);

    // layer 1
    tg71_prop_first<<<gP, TG_BT, 0, stream>>>(rowptr, srcS, cnt, dis, x, flags, 0, A);
    tg71_prop<<<gP, TG_BT, 0, stream>>>(rowptr, srcS, cnt, A, B);
    tg71_prop<<<gP, TG_BT, 0, stream>>>(rowptr, srcS, cnt, B, C);
    tg71_gemm_tiled<<<gT, TG_BT, 0, stream>>>(x, 0, A, B, C, W1, b1, cnt, flags,
                                              Y, 0, nullptr, nullptr, nullptr);

    // layer 2 + head
    tg71_prop_first<<<gP, TG_BT, 0, stream>>>(rowptr, srcS, cnt, dis, Y, flags, 1, A);
    tg71_prop<<<gP, TG_BT, 0, stream>>>(rowptr, srcS, cnt, A, B);
    tg71_prop<<<gP, TG_BT, 0, stream>>>(rowptr, srcS, cnt, B, C);
    tg71_gemm_tiled<<<gT, TG_BT, 0, stream>>>(Y, 1, A, B, C, W2, b2, cnt, flags,
                                              nullptr, 1, Wc, bc, d_out);
}

// Round 6
// 812.940 us; speedup vs baseline: 6.1380x; 6.1380x over previous
//
#include <hip/hip_runtime.h>
#include <hip/hip_bf16.h>

static constexpr int TG_NN = 100000;
static constexpr int TG_NE = 1200000;
static constexpr int TG_D  = 64;
static constexpr int TG_NC = 40;
static constexpr int TG_BT = 256;
static constexpr int TG_NP = (TG_NN + 1023) / 1024;  // scan blocks (98)

// ---- dtype-flexible load/store (isF32: 1 = fp32 storage, 0 = bf16) ----
__device__ __forceinline__ float tg71_ld(const void* p, long i, int isF32) {
    if (isF32) return ((const float*)p)[i];
    return __uint_as_float(((unsigned int)((const unsigned short*)p)[i]) << 16);
}
__device__ __forceinline__ void tg71_st(void* p, long i, int isF32, float v) {
    if (isF32) ((float*)p)[i] = v;
    else ((__hip_bfloat16*)p)[i] = __float2bfloat16(v);
}
__device__ __forceinline__ float4 tg71_ld4(const void* p, long i, int isF32) {
    if (isF32) return *(const float4*)((const float*)p + i);
    ushort4 u = *(const ushort4*)((const unsigned short*)p + i);
    float4 r;
    r.x = __uint_as_float(((unsigned int)u.x) << 16);
    r.y = __uint_as_float(((unsigned int)u.y) << 16);
    r.z = __uint_as_float(((unsigned int)u.z) << 16);
    r.w = __uint_as_float(((unsigned int)u.w) << 16);
    return r;
}
__device__ __forceinline__ float tg71_f4c(const float4& v, int k) {
    switch (k) { case 0: return v.x; case 1: return v.y; case 2: return v.z; default: return v.w; }
}

// flags[0] = edge_index is int64 ; flags[1] = float tensors are fp32
__global__ void tg71_detect(const int* ei, const unsigned short* w1bits, int* flags) {
    if (threadIdx.x == 0 && blockIdx.x == 0) {
        int i64 = 1;
        for (int k = 0; k < 64; ++k)
            if (ei[2 * k + 1] != 0) { i64 = 0; break; }
        flags[0] = i64;
        int f32 = 0;
        for (int k = 0; k < 2048; ++k) {
            float v = __uint_as_float(((unsigned int)w1bits[k]) << 16);
            if (!(v == v) || fabsf(v) > 1e4f) { f32 = 1; break; }
        }
        flags[1] = f32;
    }
}

// Sentinel fill (diagnostic; overwritten by the fused head).
extern "C" __global__ void TAGModel_71227737636876_kernel(void* out, const int* flags) {
    long i = (long)blockIdx.x * blockDim.x + threadIdx.x;
    if (i < (long)TG_NN * TG_NC) tg71_st(out, i, flags[1], 123.0f);
}

__global__ void tg71_edges(const int* ei, const int* flags, int* srcI, int* dstI) {
    int e = blockIdx.x * blockDim.x + threadIdx.x;
    if (e >= TG_NE) return;
    if (flags[0]) { srcI[e] = ei[2 * e]; dstI[e] = ei[2 * TG_NE + 2 * e]; }
    else          { srcI[e] = ei[e];     dstI[e] = ei[TG_NE + e]; }
}

__global__ void tg71_zero_i(int* p, int n) {
    int i = blockIdx.x * blockDim.x + threadIdx.x;
    if (i < n) p[i] = 0;
}

__global__ void tg71_hist(const int* dstI, int* cnt) {
    int e = blockIdx.x * blockDim.x + threadIdx.x;
    if (e < TG_NE) atomicAdd(cnt + dstI[e], 1);
}

__global__ void tg71_dis(const int* cnt, float* dis) {
    int i = blockIdx.x * blockDim.x + threadIdx.x;
    if (i < TG_NN) { int c = cnt[i]; dis[i] = c > 0 ? rsqrtf((float)c) : 0.0f; }
}

// ---- hierarchical exclusive scan of cnt[NN] -> rowptr[NN+1] ----
__global__ void tg71_scan1(const int* cnt, int* rowptr, int* part) {
    __shared__ int sh[256];
    int t = threadIdx.x;
    int base = blockIdx.x * 1024 + t * 4;
    int v0 = base + 0 < TG_NN ? cnt[base + 0] : 0;
    int v1 = base + 1 < TG_NN ? cnt[base + 1] : 0;
    int v2 = base + 2 < TG_NN ? cnt[base + 2] : 0;
    int v3 = base + 3 < TG_NN ? cnt[base + 3] : 0;
    int p1 = v0, p2 = v0 + v1, p3 = v0 + v1 + v2, sum = p3 + v3;
    sh[t] = sum;
    __syncthreads();
    for (int off = 1; off < 256; off <<= 1) {
        int x = (t >= off) ? sh[t - off] : 0;
        __syncthreads();
        if (t >= off) sh[t] += x;
        __syncthreads();
    }
    int ex = sh[t] - sum;
    if (base + 0 < TG_NN) rowptr[base + 0] = ex;
    if (base + 1 < TG_NN) rowptr[base + 1] = ex + p1;
    if (base + 2 < TG_NN) rowptr[base + 2] = ex + p2;
    if (base + 3 < TG_NN) rowptr[base + 3] = ex + p3;
    if (t == 255) part[blockIdx.x] = sh[255];
}

__global__ void tg71_scan2(int* part) {
    __shared__ int sh[128];
    int t = threadIdx.x;
    int v = t < TG_NP ? part[t] : 0;
    sh[t] = v;
    __syncthreads();
    for (int off = 1; off < 128; off <<= 1) {
        int x = (t >= off) ? sh[t - off] : 0;
        __syncthreads();
        if (t >= off) sh[t] += x;
        __syncthreads();
    }
    if (t < TG_NP) part[t] = sh[t] - v;
}

__global__ void tg71_scan3(int* rowptr, const int* part, int* fill) {
    int i = blockIdx.x * blockDim.x + threadIdx.x;
    if (i < TG_NN) {
        int r = rowptr[i] + part[i >> 10];
        rowptr[i] = r;
        fill[i] = r;
    }
    if (i == 0) rowptr[TG_NN] = TG_NE;
}

__global__ void tg71_scatter(const int* srcI, const int* dstI, int* fill, int* srcS) {
    int e = blockIdx.x * blockDim.x + threadIdx.x;
    if (e >= TG_NE) return;
    int pos = atomicAdd(fill + dstI[e], 1);
    srcS[pos] = srcI[e];
}

// ---- propagation (true hops): h'[n] = dis[n] * sum_{src->n} dis[src]*h[src] ----
// mode 0: h dtype from flags (model input x); mode 1: h is f32
__global__ void tg71_prop(const int* rowptr, const int* srcS, const float* dis,
                          const void* h, const int* flags, int mode, float* out) {
    int gid = blockIdx.x * blockDim.x + threadIdx.x;
    int n = gid >> 6, lane = gid & 63;
    int isF32 = mode ? 1 : flags[1];
    int r0 = rowptr[n], r1 = rowptr[n + 1];
    float acc = 0.0f;
    int k = r0;
    for (; k + 4 <= r1; k += 4) {
        int s0 = srcS[k], s1 = srcS[k + 1], s2 = srcS[k + 2], s3 = srcS[k + 3];
        float d0 = dis[s0], d1 = dis[s1], d2 = dis[s2], d3 = dis[s3];
        float a0 = tg71_ld(h, (long)s0 * TG_D + lane, isF32) * d0;
        float a1 = tg71_ld(h, (long)s1 * TG_D + lane, isF32) * d1;
        float a2 = tg71_ld(h, (long)s2 * TG_D + lane, isF32) * d2;
        float a3 = tg71_ld(h, (long)s3 * TG_D + lane, isF32) * d3;
        acc += (a0 + a1) + (a2 + a3);
    }
    for (; k < r1; ++k) {
        int s = srcS[k];
        acc += tg71_ld(h, (long)s * TG_D + lane, isF32) * dis[s];
    }
    out[(long)n * TG_D + lane] = acc * dis[n];
}

// ---- tiled GEMM: 128-node M-tile, N=64, K=256 (4 segments) ----
// y[n][j] = relu(b[j] + sum_k hop_k[n] @ W[k*64:(k+1)*64, j])
// doHead: out[n][c] = bc[c] + z[n,:]·Wc[:,c] (z kept in LDS)
__global__ __launch_bounds__(256) void tg71_gemm(
    const void* h0, int h0IsF32, const float* g1, const float* g2, const float* g3,
    const void* W, const void* bias, const int* flags,
    float* yOut, int doHead, const void* Wc, const void* bc, void* outp) {
    __shared__ float sW[64 * 64];     // 16 KB: one W K-segment (also reused for Wc^T + bc)
    __shared__ float sH[128 * 68];    // 34 KB: h tile (pitch 68 for bank spread), reused for z

    const int t  = threadIdx.x;
    const int jb = t & 7;             // 0..7  -> cols j0..j0+7
    const int mb = t >> 3;            // 0..31 -> nodes mb + 32*i, i=0..3
    const int j0 = jb * 8;
    const int fF = flags[1];
    const long tile = (long)blockIdx.x * 128;

    float4 aLo[4], aHi[4];
#pragma unroll
    for (int i = 0; i < 4; ++i) {
        aLo[i] = float4{0.f, 0.f, 0.f, 0.f};
        aHi[i] = float4{0.f, 0.f, 0.f, 0.f};
    }

    for (int seg = 0; seg < 4; ++seg) {
        const void* hs = (seg == 0) ? h0 : (seg == 1 ? (const void*)g1 : (seg == 2 ? (const void*)g2 : (const void*)g3));
        const int hf = (seg == 0) ? (h0IsF32 ? 1 : fF) : 1;
        if (seg) __syncthreads();   // protect previous segment's LDS from overwrite
        // stage W segment (vectorized, linear copy)
        for (int i = t * 4; i < 64 * 64; i += 1024)
            *(float4*)&sW[i] = tg71_ld4(W, (long)seg * 4096 + i, fF);
        // stage h tile: rows [tile, tile+128)
        for (int i = t * 4; i < 128 * 64; i += 1024) {
            int m = i >> 6, f = i & 63;
            long n = tile + m;
            float4 hv = (n < TG_NN) ? tg71_ld4(hs, n * TG_D + f, hf) : float4{0.f, 0.f, 0.f, 0.f};
            *(float4*)&sH[m * 68 + f] = hv;
        }
        __syncthreads();
        // compute
        for (int fc = 0; fc < 64; fc += 4) {
            float4 hv[4];
#pragma unroll
            for (int i = 0; i < 4; ++i)
                hv[i] = *(const float4*)&sH[(mb + 32 * i) * 68 + fc];
#pragma unroll
            for (int ff = 0; ff < 4; ++ff) {
                float4 wLo = *(const float4*)&sW[(fc + ff) * 64 + j0];
                float4 wHi = *(const float4*)&sW[(fc + ff) * 64 + j0 + 4];
#pragma unroll
                for (int i = 0; i < 4; ++i) {
                    float hsv = tg71_f4c(hv[i], ff);
                    aLo[i].x += hsv * wLo.x; aLo[i].y += hsv * wLo.y;
                    aLo[i].z += hsv * wLo.z; aLo[i].w += hsv * wLo.w;
                    aHi[i].x += hsv * wHi.x; aHi[i].y += hsv * wHi.y;
                    aHi[i].z += hsv * wHi.z; aHi[i].w += hsv * wHi.w;
                }
            }
        }
    }

    // epilogue: bias + relu
    float4 bLo, bHi;
    bLo.x = tg71_ld(bias, j0 + 0, fF); bLo.y = tg71_ld(bias, j0 + 1, fF);
    bLo.z = tg71_ld(bias, j0 + 2, fF); bLo.w = tg71_ld(bias, j0 + 3, fF);
    bHi.x = tg71_ld(bias, j0 + 4, fF); bHi.y = tg71_ld(bias, j0 + 5, fF);
    bHi.z = tg71_ld(bias, j0 + 6, fF); bHi.w = tg71_ld(bias, j0 + 7, fF);
#pragma unroll
    for (int i = 0; i < 4; ++i) {
        aLo[i].x = fmaxf(aLo[i].x + bLo.x, 0.f); aLo[i].y = fmaxf(aLo[i].y + bLo.y, 0.f);
        aLo[i].z = fmaxf(aLo[i].z + bLo.z, 0.f); aLo[i].w = fmaxf(aLo[i].w + bLo.w, 0.f);
        aHi[i].x = fmaxf(aHi[i].x + bHi.x, 0.f); aHi[i].y = fmaxf(aHi[i].y + bHi.y, 0.f);
        aHi[i].z = fmaxf(aHi[i].z + bHi.z, 0.f); aHi[i].w = fmaxf(aHi[i].w + bHi.w, 0.f);
    }

    if (!doHead) {
#pragma unroll
        for (int i = 0; i < 4; ++i) {
            long n = tile + mb + 32 * i;
            if (n < TG_NN) {
                *(float4*)&yOut[n * TG_D + j0]     = aLo[i];
                *(float4*)&yOut[n * TG_D + j0 + 4] = aHi[i];
            }
        }
        return;
    }

    // fused head: park z in sH, stage Wc^T + bc in sW
    __syncthreads();  // everyone done reading sH/sW
#pragma unroll
    for (int i = 0; i < 4; ++i) {
        *(float4*)&sH[(mb + 32 * i) * 68 + j0]     = aLo[i];
        *(float4*)&sH[(mb + 32 * i) * 68 + j0 + 4] = aHi[i];
    }
    for (int i = t; i < 64 * TG_NC; i += 256) {
        int f = i / TG_NC, c = i - f * TG_NC;
        sW[c * 68 + f] = tg71_ld(Wc, i, fF);
    }
    if (t < TG_NC) sW[40 * 68 + t] = tg71_ld(bc, t, fF);
    __syncthreads();

    // head compute: 4 nodes (mb+32i) x 5 cols (jb*5+q)
    float hacc[4][5];
#pragma unroll
    for (int i = 0; i < 4; ++i)
#pragma unroll
        for (int q = 0; q < 5; ++q) hacc[i][q] = 0.f;
    for (int fc = 0; fc < 64; fc += 4) {
        float4 zv[4], wv[5];
#pragma unroll
        for (int i = 0; i < 4; ++i) zv[i] = *(const float4*)&sH[(mb + 32 * i) * 68 + fc];
#pragma unroll
        for (int q = 0; q < 5; ++q) wv[q] = *(const float4*)&sW[(jb * 5 + q) * 68 + fc];
#pragma unroll
        for (int i = 0; i < 4; ++i)
#pragma unroll
            for (int q = 0; q < 5; ++q) {
                hacc[i][q] += zv[i].x * wv[q].x + zv[i].y * wv[q].y +
                              zv[i].z * wv[q].z + zv[i].w * wv[q].w;
            }
    }
#pragma unroll
    for (int i = 0; i < 4; ++i) {
        long n = tile + mb + 32 * i;
        if (n < TG_NN) {
#pragma unroll
            for (int q = 0; q < 5; ++q) {
                int c = jb * 5 + q;
                tg71_st(outp, n * TG_NC + c, fF, hacc[i][q] + sW[40 * 68 + c]);
            }
        }
    }
}

extern "C" void kernel_launch(void* const* d_in, const int* in_sizes, int n_in,
                              void* d_out, int out_size, void* d_ws, size_t ws_size,
                              hipStream_t stream) {
    const void* x  = d_in[0];
    const int*  ei = (const int*)d_in[1];
    const void* W1 = d_in[2];
    const void* b1 = d_in[3];
    const void* W2 = d_in[4];
    const void* b2 = d_in[5];
    const void* Wc = d_in[6];
    const void* bc = d_in[7];

    // workspace layout (4-byte words) ~119 MB
    int*   flags  = (int*)d_ws;                     // [16]
    int*   srcI   = flags + 16;                     // [NE]
    int*   dstI   = srcI + TG_NE;                   // [NE]
    int*   srcS   = dstI + TG_NE;                   // [NE]
    int*   cnt    = srcS + TG_NE;                   // [NN]
    float* dis    = (float*)(cnt + TG_NN);          // [NN]
    int*   rowptr = (int*)(dis + TG_NN);            // [NN+1]
    int*   fill   = rowptr + TG_NN + 1;             // [NN]
    int*   part   = fill + TG_NN;                   // [128]
    float* A      = (float*)(part + 128);           // [NN*D]
    float* B      = A + (long)TG_NN * TG_D;         // [NN*D]
    float* C      = B + (long)TG_NN * TG_D;         // [NN*D]
    float* Y      = C + (long)TG_NN * TG_D;         // [NN*D]

    const int gE  = (TG_NE + TG_BT - 1) / TG_BT;
    const int gN  = (TG_NN + TG_BT - 1) / TG_BT;
    const int gP  = TG_NN * TG_D / TG_BT;           // 25000
    const int gNC = (TG_NN * TG_NC + TG_BT - 1) / TG_BT;
    const int gT  = (TG_NN + 127) / 128;            // 782 gemm tiles

    tg71_detect<<<1, 64, 0, stream>>>(ei, (const unsigned short*)W1, flags);
    TAGModel_71227737636876_kernel<<<gNC, TG_BT, 0, stream>>>(d_out, flags);

    // CSR build
    tg71_edges<<<gE, TG_BT, 0, stream>>>(ei, flags, srcI, dstI);
    tg71_zero_i<<<gN, TG_BT, 0, stream>>>(cnt, TG_NN);
    tg71_hist<<<gE, TG_BT, 0, stream>>>(dstI, cnt);
    tg71_dis<<<gN, TG_BT, 0, stream>>>(cnt, dis);
    tg71_scan1<<<TG_NP, TG_BT, 0, stream>>>(cnt, rowptr, part);
    tg71_scan2<<<1, 128, 0, stream>>>(part);
    tg71_scan3<<<gN, TG_BT, 0, stream>>>(rowptr, part, fill);
    tg71_scatter<<<gE, TG_BT, 0, stream>>>(srcI, dstI, fill, srcS);

    // layer 1: hops are true h_k now
    tg71_prop<<<gP, TG_BT, 0, stream>>>(rowptr, srcS, dis, x, flags, 0, A);
    tg71_prop<<<gP, TG_BT, 0, stream>>>(rowptr, srcS, dis, A, flags, 1, B);
    tg71_prop<<<gP, TG_BT, 0, stream>>>(rowptr, srcS, dis, B, flags, 1, C);
    tg71_gemm<<<gT, TG_BT, 0, stream>>>(x, 0, A, B, C, W1, b1, flags,
                                        Y, 0, nullptr, nullptr, nullptr);

    // layer 2 + fused head
    tg71_prop<<<gP, TG_BT, 0, stream>>>(rowptr, srcS, dis, Y, flags, 1, A);
    tg71_prop<<<gP, TG_BT, 0, stream>>>(rowptr, srcS, dis, A, flags, 1, B);
    tg71_prop<<<gP, TG_BT, 0, stream>>>(rowptr, srcS, dis, B, flags, 1, C);
    tg71_gemm<<<gT, TG_BT, 0, stream>>>(Y, 1, A, B, C, W2, b2, flags,
                                        nullptr, 1, Wc, bc, d_out);
}

// Round 8
// 659.480 us; speedup vs baseline: 7.5663x; 1.2327x over previous
//
#include <hip/hip_runtime.h>
#include <hip/hip_bf16.h>
#include <stdint.h>

static constexpr int TG_NN = 100000;
static constexpr int TG_NE = 1200000;
static constexpr int TG_D  = 64;
static constexpr int TG_NC = 40;
static constexpr int TG_BT = 256;
static constexpr int TG_NP = (TG_NN + 1023) / 1024;  // scan blocks (98)

// ---- dtype helpers ----
__device__ __forceinline__ float tg71_b2f(unsigned short u) {
    return __uint_as_float(((unsigned int)u) << 16);
}
__device__ __forceinline__ unsigned short tg71_f2b(float v) {
    __hip_bfloat16 b = __float2bfloat16(v);  // RNE
    return __builtin_bit_cast(unsigned short, b);
}
__device__ __forceinline__ float tg71_ld(const void* p, long i, int isF32) {
    if (isF32) return ((const float*)p)[i];
    return tg71_b2f(((const unsigned short*)p)[i]);
}
__device__ __forceinline__ void tg71_st(void* p, long i, int isF32, float v) {
    if (isF32) ((float*)p)[i] = v;
    else ((unsigned short*)p)[i] = tg71_f2b(v);
}
__device__ __forceinline__ float4 tg71_ld4(const void* p, long i, int isF32) {
    if (isF32) return *(const float4*)((const float*)p + i);
    ushort4 u = *(const ushort4*)((const unsigned short*)p + i);
    return float4{tg71_b2f(u.x), tg71_b2f(u.y), tg71_b2f(u.z), tg71_b2f(u.w)};
}
__device__ __forceinline__ ushort4 tg71_pack4(float4 v) {
    return ushort4{tg71_f2b(v.x), tg71_f2b(v.y), tg71_f2b(v.z), tg71_f2b(v.w)};
}
__device__ __forceinline__ float tg71_f4c(const float4& v, int k) {
    switch (k) { case 0: return v.x; case 1: return v.y; case 2: return v.z; default: return v.w; }
}

// flags[0] = edge_index is int64 ; flags[1] = float tensors are fp32
__global__ void tg71_detect(const int* ei, const unsigned short* w1bits, int* flags) {
    int lane = threadIdx.x;  // 64 threads
    int hi = ei[2 * lane + 1];
    unsigned long long bi = __ballot(hi != 0);
    float mx = 0.0f;
    for (int k = lane; k < 2048; k += 64) {
        float v = fabsf(tg71_b2f(w1bits[k]));
        if (!(v == v)) v = 1e30f;
        mx = fmaxf(mx, v);
    }
    unsigned long long bf = __ballot(mx > 1e4f);
    if (lane == 0) { flags[0] = (bi == 0ULL) ? 1 : 0; flags[1] = (bf != 0ULL) ? 1 : 0; }
}

// Kept for pipeline symbol validation; not launched (head writes all outputs).
extern "C" __global__ void TAGModel_71227737636876_kernel(void* out, const int* flags) {
    long i = (long)blockIdx.x * blockDim.x + threadIdx.x;
    if (i < (long)TG_NN * TG_NC) tg71_st(out, i, flags[1], 123.0f);
}

__global__ void tg71_edges(const int* ei, const int* flags, int* srcI, int* dstI) {
    int e = blockIdx.x * blockDim.x + threadIdx.x;
    if (e >= TG_NE) return;
    if (flags[0]) { srcI[e] = ei[2 * e]; dstI[e] = ei[2 * TG_NE + 2 * e]; }
    else          { srcI[e] = ei[e];     dstI[e] = ei[TG_NE + e]; }
}

__global__ void tg71_zero_i(int* p, int n) {
    int i = blockIdx.x * blockDim.x + threadIdx.x;
    if (i < n) p[i] = 0;
}

__global__ void tg71_hist(const int* dstI, int* cnt) {
    int e = blockIdx.x * blockDim.x + threadIdx.x;
    if (e < TG_NE) atomicAdd(cnt + dstI[e], 1);
}

__global__ void tg71_dis(const int* cnt, float* dis) {
    int i = blockIdx.x * blockDim.x + threadIdx.x;
    if (i < TG_NN) { int c = cnt[i]; dis[i] = c > 0 ? rsqrtf((float)c) : 0.0f; }
}

// ---- hierarchical exclusive scan of cnt[NN] -> rowptr[NN+1] ----
__global__ void tg71_scan1(const int* cnt, int* rowptr, int* part) {
    __shared__ int sh[256];
    int t = threadIdx.x;
    int base = blockIdx.x * 1024 + t * 4;
    int v0 = base + 0 < TG_NN ? cnt[base + 0] : 0;
    int v1 = base + 1 < TG_NN ? cnt[base + 1] : 0;
    int v2 = base + 2 < TG_NN ? cnt[base + 2] : 0;
    int v3 = base + 3 < TG_NN ? cnt[base + 3] : 0;
    int p1 = v0, p2 = v0 + v1, p3 = v0 + v1 + v2, sum = p3 + v3;
    sh[t] = sum;
    __syncthreads();
    for (int off = 1; off < 256; off <<= 1) {
        int x = (t >= off) ? sh[t - off] : 0;
        __syncthreads();
        if (t >= off) sh[t] += x;
        __syncthreads();
    }
    int ex = sh[t] - sum;
    if (base + 0 < TG_NN) rowptr[base + 0] = ex;
    if (base + 1 < TG_NN) rowptr[base + 1] = ex + p1;
    if (base + 2 < TG_NN) rowptr[base + 2] = ex + p2;
    if (base + 3 < TG_NN) rowptr[base + 3] = ex + p3;
    if (t == 255) part[blockIdx.x] = sh[255];
}

__global__ void tg71_scan2(int* part) {
    __shared__ int sh[128];
    int t = threadIdx.x;
    int v = t < TG_NP ? part[t] : 0;
    sh[t] = v;
    __syncthreads();
    for (int off = 1; off < 128; off <<= 1) {
        int x = (t >= off) ? sh[t - off] : 0;
        __syncthreads();
        if (t >= off) sh[t] += x;
        __syncthreads();
    }
    if (t < TG_NP) part[t] = sh[t] - v;
}

__global__ void tg71_scan3(int* rowptr, const int* part, int* fill) {
    int i = blockIdx.x * blockDim.x + threadIdx.x;
    if (i < TG_NN) {
        int r = rowptr[i] + part[i >> 10];
        rowptr[i] = r;
        fill[i] = r;
    }
    if (i == 0) rowptr[TG_NN] = TG_NE;
}

__global__ void tg71_scatter(const int* srcI, const int* dstI, int* fill, int* srcS) {
    int e = blockIdx.x * blockDim.x + threadIdx.x;
    if (e >= TG_NE) return;
    int pos = atomicAdd(fill + dstI[e], 1);
    srcS[pos] = srcI[e];
}

// ---- propagation: h'[n] = bf16( dis[n] * sum_{src->n} dis[src]*h[src] ) ----
// 4 nodes per wave (16-lane groups, 4 features/lane).
// mode 0: h dtype follows flags (model input x); mode 1: h is bf16 hop buffer.
__global__ void tg71_prop(const int* __restrict__ rowptr, const int* __restrict__ srcS,
                          const float* __restrict__ dis, const void* __restrict__ h,
                          const int* flags, int mode, unsigned short* __restrict__ out) {
    int gid = blockIdx.x * blockDim.x + threadIdx.x;
    int wid = gid >> 6;            // global wave id (0..24999)
    int lane = gid & 63;
    int g = lane >> 4;             // group 0..3
    int li = lane & 15;            // lane in group
    int n = wid * 4 + g;           // NN divisible by 4 -> always < NN
    int isF32 = (mode == 0) ? flags[1] : 0;

    int r0 = rowptr[n], r1 = rowptr[n + 1];
    float4 acc = float4{0.f, 0.f, 0.f, 0.f};
    long fo = (long)li * 4;
    int k = r0;
    for (; k + 4 <= r1; k += 4) {
        int s0 = srcS[k], s1 = srcS[k + 1], s2 = srcS[k + 2], s3 = srcS[k + 3];
        float d0 = dis[s0], d1 = dis[s1], d2 = dis[s2], d3 = dis[s3];
        float4 a0 = tg71_ld4(h, (long)s0 * TG_D + fo, isF32);
        float4 a1 = tg71_ld4(h, (long)s1 * TG_D + fo, isF32);
        float4 a2 = tg71_ld4(h, (long)s2 * TG_D + fo, isF32);
        float4 a3 = tg71_ld4(h, (long)s3 * TG_D + fo, isF32);
        acc.x += a0.x * d0 + a1.x * d1 + a2.x * d2 + a3.x * d3;
        acc.y += a0.y * d0 + a1.y * d1 + a2.y * d2 + a3.y * d3;
        acc.z += a0.z * d0 + a1.z * d1 + a2.z * d2 + a3.z * d3;
        acc.w += a0.w * d0 + a1.w * d1 + a2.w * d2 + a3.w * d3;
    }
    for (; k < r1; ++k) {
        int s = srcS[k];
        float d = dis[s];
        float4 a = tg71_ld4(h, (long)s * TG_D + fo, isF32);
        acc.x += a.x * d; acc.y += a.y * d; acc.z += a.z * d; acc.w += a.w * d;
    }
    float dn = dis[n];
    acc.x *= dn; acc.y *= dn; acc.z *= dn; acc.w *= dn;
    *(ushort4*)&out[(long)n * TG_D + fo] = tg71_pack4(acc);
}

// ---- tiled GEMM: 128-node M-tile, N=64, K=256 (4 segments) ----
// y[n][j] = relu(b[j] + sum_k hop_k[n] @ W[k*64:(k+1)*64, j]); y stored bf16.
// h0Mode: 0 = follow flags (model input x), 1 = always fp32, 2 = always bf16.
// doHead: out[n][c] = bc[c] + z[n,:]·Wc[:,c] (z parked in LDS as bf16)
__global__ __launch_bounds__(256) void tg71_gemm(
    const void* h0, int h0Mode, const unsigned short* g1, const unsigned short* g2,
    const unsigned short* g3, const void* W, const void* bias, const int* flags,
    unsigned short* yOut, int doHead, const void* Wc, const void* bc, void* outp) {
    __shared__ float sW[64 * 64];            // 16 KB: W K-segment fp32 (reused: Wc^T + bc)
    __shared__ unsigned short sH[128 * 68];  // 17.4 KB: h tile bf16 (reused for z)

    const int t  = threadIdx.x;
    const int jb = t & 7;             // 0..7  -> cols j0..j0+7
    const int mb = t >> 3;            // 0..31 -> nodes mb + 32*i
    const int j0 = jb * 8;
    const int fF = flags[1];
    const int h0F32 = (h0Mode == 1) ? 1 : (h0Mode == 2 ? 0 : fF);
    const long tile = (long)blockIdx.x * 128;

    float4 aLo[4], aHi[4];
#pragma unroll
    for (int i = 0; i < 4; ++i) {
        aLo[i] = float4{0.f, 0.f, 0.f, 0.f};
        aHi[i] = float4{0.f, 0.f, 0.f, 0.f};
    }

    for (int seg = 0; seg < 4; ++seg) {
        const int hf = (seg == 0) ? h0F32 : 0;
        const void* hs = (seg == 0) ? h0
                       : (seg == 1 ? (const void*)g1 : (seg == 2 ? (const void*)g2 : (const void*)g3));
        if (seg) __syncthreads();
        // stage W segment -> fp32 LDS
        for (int i = t * 4; i < 64 * 64; i += 1024)
            *(float4*)&sW[i] = tg71_ld4(W, (long)seg * 4096 + i, fF);
        // stage h tile -> bf16 LDS (pitch 68)
        for (int i = t * 4; i < 128 * 64; i += 1024) {
            int m = i >> 6, f = i & 63;
            long n = tile + m;
            ushort4 hv;
            if (n < TG_NN) {
                if (hf) hv = tg71_pack4(*(const float4*)((const float*)hs + n * TG_D + f));
                else    hv = *(const ushort4*)((const unsigned short*)hs + n * TG_D + f);
            } else hv = ushort4{0, 0, 0, 0};
            *(ushort4*)&sH[m * 68 + f] = hv;
        }
        __syncthreads();
        for (int fc = 0; fc < 64; fc += 4) {
            float4 hv[4];
#pragma unroll
            for (int i = 0; i < 4; ++i) {
                ushort4 u = *(const ushort4*)&sH[(mb + 32 * i) * 68 + fc];
                hv[i] = float4{tg71_b2f(u.x), tg71_b2f(u.y), tg71_b2f(u.z), tg71_b2f(u.w)};
            }
#pragma unroll
            for (int ff = 0; ff < 4; ++ff) {
                float4 wLo = *(const float4*)&sW[(fc + ff) * 64 + j0];
                float4 wHi = *(const float4*)&sW[(fc + ff) * 64 + j0 + 4];
#pragma unroll
                for (int i = 0; i < 4; ++i) {
                    float hsv = tg71_f4c(hv[i], ff);
                    aLo[i].x += hsv * wLo.x; aLo[i].y += hsv * wLo.y;
                    aLo[i].z += hsv * wLo.z; aLo[i].w += hsv * wLo.w;
                    aHi[i].x += hsv * wHi.x; aHi[i].y += hsv * wHi.y;
                    aHi[i].z += hsv * wHi.z; aHi[i].w += hsv * wHi.w;
                }
            }
        }
    }

    // epilogue: bias + relu
    float4 bLo, bHi;
    bLo.x = tg71_ld(bias, j0 + 0, fF); bLo.y = tg71_ld(bias, j0 + 1, fF);
    bLo.z = tg71_ld(bias, j0 + 2, fF); bLo.w = tg71_ld(bias, j0 + 3, fF);
    bHi.x = tg71_ld(bias, j0 + 4, fF); bHi.y = tg71_ld(bias, j0 + 5, fF);
    bHi.z = tg71_ld(bias, j0 + 6, fF); bHi.w = tg71_ld(bias, j0 + 7, fF);
#pragma unroll
    for (int i = 0; i < 4; ++i) {
        aLo[i].x = fmaxf(aLo[i].x + bLo.x, 0.f); aLo[i].y = fmaxf(aLo[i].y + bLo.y, 0.f);
        aLo[i].z = fmaxf(aLo[i].z + bLo.z, 0.f); aLo[i].w = fmaxf(aLo[i].w + bLo.w, 0.f);
        aHi[i].x = fmaxf(aHi[i].x + bHi.x, 0.f); aHi[i].y = fmaxf(aHi[i].y + bHi.y, 0.f);
        aHi[i].z = fmaxf(aHi[i].z + bHi.z, 0.f); aHi[i].w = fmaxf(aHi[i].w + bHi.w, 0.f);
    }

    if (!doHead) {
#pragma unroll
        for (int i = 0; i < 4; ++i) {
            long n = tile + mb + 32 * i;
            if (n < TG_NN) {
                *(ushort4*)&yOut[n * TG_D + j0]     = tg71_pack4(aLo[i]);
                *(ushort4*)&yOut[n * TG_D + j0 + 4] = tg71_pack4(aHi[i]);
            }
        }
        return;
    }

    // fused head: park z (bf16) in sH, stage Wc^T (fp32) + bc in sW
    __syncthreads();
#pragma unroll
    for (int i = 0; i < 4; ++i) {
        *(ushort4*)&sH[(mb + 32 * i) * 68 + j0]     = tg71_pack4(aLo[i]);
        *(ushort4*)&sH[(mb + 32 * i) * 68 + j0 + 4] = tg71_pack4(aHi[i]);
    }
    for (int i = t; i < 64 * TG_NC; i += 256) {
        int f = i / TG_NC, c = i - f * TG_NC;
        sW[c * 68 + f] = tg71_ld(Wc, i, fF);
    }
    if (t < TG_NC) sW[40 * 68 + t] = tg71_ld(bc, t, fF);
    __syncthreads();

    float hacc[4][5];
#pragma unroll
    for (int i = 0; i < 4; ++i)
#pragma unroll
        for (int q = 0; q < 5; ++q) hacc[i][q] = 0.f;
    for (int fc = 0; fc < 64; fc += 4) {
        float4 zv[4], wv[5];
#pragma unroll
        for (int i = 0; i < 4; ++i) {
            ushort4 u = *(const ushort4*)&sH[(mb + 32 * i) * 68 + fc];
            zv[i] = float4{tg71_b2f(u.x), tg71_b2f(u.y), tg71_b2f(u.z), tg71_b2f(u.w)};
        }
#pragma unroll
        for (int q = 0; q < 5; ++q) wv[q] = *(const float4*)&sW[(jb * 5 + q) * 68 + fc];
#pragma unroll
        for (int i = 0; i < 4; ++i)
#pragma unroll
            for (int q = 0; q < 5; ++q)
                hacc[i][q] += zv[i].x * wv[q].x + zv[i].y * wv[q].y +
                              zv[i].z * wv[q].z + zv[i].w * wv[q].w;
    }
#pragma unroll
    for (int i = 0; i < 4; ++i) {
        long n = tile + mb + 32 * i;
        if (n < TG_NN) {
#pragma unroll
            for (int q = 0; q < 5; ++q) {
                int c = jb * 5 + q;
                tg71_st(outp, n * TG_NC + c, fF, hacc[i][q] + sW[40 * 68 + c]);
            }
        }
    }
}

extern "C" void kernel_launch(void* const* d_in, const int* in_sizes, int n_in,
                              void* d_out, int out_size, void* d_ws, size_t ws_size,
                              hipStream_t stream) {
    const void* x  = d_in[0];
    const int*  ei = (const int*)d_in[1];
    const void* W1 = d_in[2];
    const void* b1 = d_in[3];
    const void* W2 = d_in[4];
    const void* b2 = d_in[5];
    const void* Wc = d_in[6];
    const void* bc = d_in[7];

    // workspace layout (4-byte words); hop buffers bf16, base 16B-aligned
    int*   flags  = (int*)d_ws;                     // [16]
    int*   srcI   = flags + 16;                     // [NE]
    int*   dstI   = srcI + TG_NE;                   // [NE]
    int*   srcS   = dstI + TG_NE;                   // [NE]
    int*   cnt    = srcS + TG_NE;                   // [NN]
    float* dis    = (float*)(cnt + TG_NN);          // [NN]
    int*   rowptr = (int*)(dis + TG_NN);            // [NN+1]
    int*   fill   = rowptr + TG_NN + 1;             // [NN]
    int*   part   = fill + TG_NN;                   // [128]
    unsigned short* A = (unsigned short*)(((uintptr_t)(part + 128) + 15) & ~(uintptr_t)15);
    unsigned short* B = A + (long)TG_NN * TG_D;              // [NN*D] bf16
    unsigned short* C = B + (long)TG_NN * TG_D;              // [NN*D] bf16
    unsigned short* Y = C + (long)TG_NN * TG_D;              // [NN*D] bf16

    const int gE  = (TG_NE + TG_BT - 1) / TG_BT;
    const int gN  = (TG_NN + TG_BT - 1) / TG_BT;
    const int gP  = TG_NN / 4 * 64 / TG_BT;         // 6250: 4 nodes/wave
    const int gT  = (TG_NN + 127) / 128;            // 782 gemm tiles

    tg71_detect<<<1, 64, 0, stream>>>(ei, (const unsigned short*)W1, flags);

    // CSR build
    tg71_edges<<<gE, TG_BT, 0, stream>>>(ei, flags, srcI, dstI);
    tg71_zero_i<<<gN, TG_BT, 0, stream>>>(cnt, TG_NN);
    tg71_hist<<<gE, TG_BT, 0, stream>>>(dstI, cnt);
    tg71_dis<<<gN, TG_BT, 0, stream>>>(cnt, dis);
    tg71_scan1<<<TG_NP, TG_BT, 0, stream>>>(cnt, rowptr, part);
    tg71_scan2<<<1, 128, 0, stream>>>(part);
    tg71_scan3<<<gN, TG_BT, 0, stream>>>(rowptr, part, fill);
    tg71_scatter<<<gE, TG_BT, 0, stream>>>(srcI, dstI, fill, srcS);

    // layer 1
    tg71_prop<<<gP, TG_BT, 0, stream>>>(rowptr, srcS, dis, x, flags, 0, A);
    tg71_prop<<<gP, TG_BT, 0, stream>>>(rowptr, srcS, dis, A, flags, 1, B);
    tg71_prop<<<gP, TG_BT, 0, stream>>>(rowptr, srcS, dis, B, flags, 1, C);
    tg71_gemm<<<gT, TG_BT, 0, stream>>>(x, 0, A, B, C, W1, b1, flags,
                                        Y, 0, nullptr, nullptr, nullptr);

    // layer 2 + fused head (h0 = Y is bf16 -> h0Mode 2)
    tg71_prop<<<gP, TG_BT, 0, stream>>>(rowptr, srcS, dis, Y, flags, 1, A);
    tg71_prop<<<gP, TG_BT, 0, stream>>>(rowptr, srcS, dis, A, flags, 1, B);
    tg71_prop<<<gP, TG_BT, 0, stream>>>(rowptr, srcS, dis, B, flags, 1, C);
    tg71_gemm<<<gT, TG_BT, 0, stream>>>(Y, 2, A, B, C, W2, b2, flags,
                                        nullptr, 1, Wc, bc, d_out);
}

// Round 9
// 633.781 us; speedup vs baseline: 7.8732x; 1.0405x over previous
//
#include <hip/hip_runtime.h>
#include <hip/hip_bf16.h>
#include <stdint.h>

static constexpr int TG_NN = 100000;
static constexpr int TG_NE = 1200000;
static constexpr int TG_D  = 64;
static constexpr int TG_NC = 40;
static constexpr int TG_BT = 256;
static constexpr int TG_NP = (TG_NN + 1023) / 1024;  // scan blocks (98)

// ---- dtype helpers ----
__device__ __forceinline__ float tg71_b2f(unsigned short u) {
    return __uint_as_float(((unsigned int)u) << 16);
}
__device__ __forceinline__ unsigned short tg71_f2b(float v) {
    __hip_bfloat16 b = __float2bfloat16(v);  // RNE
    return __builtin_bit_cast(unsigned short, b);
}
__device__ __forceinline__ float tg71_ld(const void* p, long i, int isF32) {
    if (isF32) return ((const float*)p)[i];
    return tg71_b2f(((const unsigned short*)p)[i]);
}
__device__ __forceinline__ void tg71_st(void* p, long i, int isF32, float v) {
    if (isF32) ((float*)p)[i] = v;
    else ((unsigned short*)p)[i] = tg71_f2b(v);
}
__device__ __forceinline__ float4 tg71_u2f4(ushort4 u) {
    return float4{tg71_b2f(u.x), tg71_b2f(u.y), tg71_b2f(u.z), tg71_b2f(u.w)};
}
__device__ __forceinline__ float4 tg71_ld4(const void* p, long i, int isF32) {
    if (isF32) return *(const float4*)((const float*)p + i);
    return tg71_u2f4(*(const ushort4*)((const unsigned short*)p + i));
}
__device__ __forceinline__ ushort4 tg71_pack4(float4 v) {
    return ushort4{tg71_f2b(v.x), tg71_f2b(v.y), tg71_f2b(v.z), tg71_f2b(v.w)};
}
__device__ __forceinline__ float tg71_f4c(const float4& v, int k) {
    switch (k) { case 0: return v.x; case 1: return v.y; case 2: return v.z; default: return v.w; }
}

// flags[0] = edge_index is int64 ; flags[1] = float tensors are fp32
__global__ void tg71_detect(const int* ei, const unsigned short* w1bits, int* flags) {
    int lane = threadIdx.x;  // 64 threads
    int hi = ei[2 * lane + 1];
    unsigned long long bi = __ballot(hi != 0);
    float mx = 0.0f;
    for (int k = lane; k < 2048; k += 64) {
        float v = fabsf(tg71_b2f(w1bits[k]));
        if (!(v == v)) v = 1e30f;
        mx = fmaxf(mx, v);
    }
    unsigned long long bf = __ballot(mx > 1e4f);
    if (lane == 0) { flags[0] = (bi == 0ULL) ? 1 : 0; flags[1] = (bf != 0ULL) ? 1 : 0; }
}

// Kept for pipeline symbol validation; not launched (head writes all outputs).
extern "C" __global__ void TAGModel_71227737636876_kernel(void* out, const int* flags) {
    long i = (long)blockIdx.x * blockDim.x + threadIdx.x;
    if (i < (long)TG_NN * TG_NC) tg71_st(out, i, flags[1], 123.0f);
}

__global__ void tg71_zero_i(int* p, int n) {
    int i = blockIdx.x * blockDim.x + threadIdx.x;
    if (i < n) p[i] = 0;
}

// edge decode + degree histogram fused (cnt must be zeroed first)
__global__ void tg71_edges(const int* ei, const int* flags, int* srcI, int* dstI, int* cnt) {
    int e = blockIdx.x * blockDim.x + threadIdx.x;
    if (e >= TG_NE) return;
    int s, d;
    if (flags[0]) { s = ei[2 * e]; d = ei[2 * TG_NE + 2 * e]; }
    else          { s = ei[e];     d = ei[TG_NE + e]; }
    srcI[e] = s;
    dstI[e] = d;
    atomicAdd(cnt + d, 1);
}

// ---- hierarchical exclusive scan of cnt[NN] -> rowptr[NN+1]; also emits dis ----
__global__ void tg71_scan1(const int* cnt, int* rowptr, int* part, float* dis) {
    __shared__ int sh[256];
    int t = threadIdx.x;
    int base = blockIdx.x * 1024 + t * 4;
    int v0 = base + 0 < TG_NN ? cnt[base + 0] : 0;
    int v1 = base + 1 < TG_NN ? cnt[base + 1] : 0;
    int v2 = base + 2 < TG_NN ? cnt[base + 2] : 0;
    int v3 = base + 3 < TG_NN ? cnt[base + 3] : 0;
    if (base + 0 < TG_NN) dis[base + 0] = v0 > 0 ? rsqrtf((float)v0) : 0.0f;
    if (base + 1 < TG_NN) dis[base + 1] = v1 > 0 ? rsqrtf((float)v1) : 0.0f;
    if (base + 2 < TG_NN) dis[base + 2] = v2 > 0 ? rsqrtf((float)v2) : 0.0f;
    if (base + 3 < TG_NN) dis[base + 3] = v3 > 0 ? rsqrtf((float)v3) : 0.0f;
    int p1 = v0, p2 = v0 + v1, p3 = v0 + v1 + v2, sum = p3 + v3;
    sh[t] = sum;
    __syncthreads();
    for (int off = 1; off < 256; off <<= 1) {
        int x = (t >= off) ? sh[t - off] : 0;
        __syncthreads();
        if (t >= off) sh[t] += x;
        __syncthreads();
    }
    int ex = sh[t] - sum;
    if (base + 0 < TG_NN) rowptr[base + 0] = ex;
    if (base + 1 < TG_NN) rowptr[base + 1] = ex + p1;
    if (base + 2 < TG_NN) rowptr[base + 2] = ex + p2;
    if (base + 3 < TG_NN) rowptr[base + 3] = ex + p3;
    if (t == 255) part[blockIdx.x] = sh[255];
}

__global__ void tg71_scan2(int* part) {
    __shared__ int sh[128];
    int t = threadIdx.x;
    int v = t < TG_NP ? part[t] : 0;
    sh[t] = v;
    __syncthreads();
    for (int off = 1; off < 128; off <<= 1) {
        int x = (t >= off) ? sh[t - off] : 0;
        __syncthreads();
        if (t >= off) sh[t] += x;
        __syncthreads();
    }
    if (t < TG_NP) part[t] = sh[t] - v;
}

__global__ void tg71_scan3(int* rowptr, const int* part, int* fill) {
    int i = blockIdx.x * blockDim.x + threadIdx.x;
    if (i < TG_NN) {
        int r = rowptr[i] + part[i >> 10];
        rowptr[i] = r;
        fill[i] = r;
    }
    if (i == 0) rowptr[TG_NN] = TG_NE;
}

// Windowed CSR scatter: pass p handles dst in [p*32768, (p+1)*32768).
// Active srcS window ~1.6 MB -> L2-resident, writes coalesce before writeback.
__global__ void tg71_scatter(const int* __restrict__ srcI, const int* __restrict__ dstI,
                             int* fill, int* srcS, int pass) {
    int e = blockIdx.x * blockDim.x + threadIdx.x;
    if (e >= TG_NE) return;
    int d = dstI[e];
    if ((d >> 15) != pass) return;
    int pos = atomicAdd(fill + d, 1);
    srcS[pos] = srcI[e];
}

// ---- propagation: h'[n] = bf16( dis[n] * sum_{src->n} dis[src]*h[src] ) ----
// 4 nodes per wave (16-lane groups, 4 features/lane).

// pure-bf16 input path (hop buffers, Y)
__global__ void tg71_prop_b(const int* __restrict__ rowptr, const int* __restrict__ srcS,
                            const float* __restrict__ dis, const unsigned short* __restrict__ h,
                            unsigned short* __restrict__ out) {
    int gid = blockIdx.x * blockDim.x + threadIdx.x;
    int wid = gid >> 6, lane = gid & 63;
    int g = lane >> 4, li = lane & 15;
    int n = wid * 4 + g;
    int r0 = rowptr[n], r1 = rowptr[n + 1];
    float4 acc = float4{0.f, 0.f, 0.f, 0.f};
    long fo = (long)li * 4;
    int k = r0;
    for (; k + 4 <= r1; k += 4) {
        int s0 = srcS[k], s1 = srcS[k + 1], s2 = srcS[k + 2], s3 = srcS[k + 3];
        float d0 = dis[s0], d1 = dis[s1], d2 = dis[s2], d3 = dis[s3];
        float4 a0 = tg71_u2f4(*(const ushort4*)&h[(long)s0 * TG_D + fo]);
        float4 a1 = tg71_u2f4(*(const ushort4*)&h[(long)s1 * TG_D + fo]);
        float4 a2 = tg71_u2f4(*(const ushort4*)&h[(long)s2 * TG_D + fo]);
        float4 a3 = tg71_u2f4(*(const ushort4*)&h[(long)s3 * TG_D + fo]);
        acc.x += a0.x * d0 + a1.x * d1 + a2.x * d2 + a3.x * d3;
        acc.y += a0.y * d0 + a1.y * d1 + a2.y * d2 + a3.y * d3;
        acc.z += a0.z * d0 + a1.z * d1 + a2.z * d2 + a3.z * d3;
        acc.w += a0.w * d0 + a1.w * d1 + a2.w * d2 + a3.w * d3;
    }
    for (; k < r1; ++k) {
        int s = srcS[k];
        float d = dis[s];
        float4 a = tg71_u2f4(*(const ushort4*)&h[(long)s * TG_D + fo]);
        acc.x += a.x * d; acc.y += a.y * d; acc.z += a.z * d; acc.w += a.w * d;
    }
    float dn = dis[n];
    acc.x *= dn; acc.y *= dn; acc.z *= dn; acc.w *= dn;
    *(ushort4*)&out[(long)n * TG_D + fo] = tg71_pack4(acc);
}

// model-input path (x may be fp32 or bf16; branch hoisted outside the loop)
__global__ void tg71_prop_x(const int* __restrict__ rowptr, const int* __restrict__ srcS,
                            const float* __restrict__ dis, const void* __restrict__ h,
                            const int* flags, unsigned short* __restrict__ out) {
    int gid = blockIdx.x * blockDim.x + threadIdx.x;
    int wid = gid >> 6, lane = gid & 63;
    int g = lane >> 4, li = lane & 15;
    int n = wid * 4 + g;
    int r0 = rowptr[n], r1 = rowptr[n + 1];
    float4 acc = float4{0.f, 0.f, 0.f, 0.f};
    long fo = (long)li * 4;
    if (flags[1]) {
        const float* hf = (const float*)h;
        for (int k = r0; k < r1; ++k) {
            int s = srcS[k];
            float d = dis[s];
            float4 a = *(const float4*)&hf[(long)s * TG_D + fo];
            acc.x += a.x * d; acc.y += a.y * d; acc.z += a.z * d; acc.w += a.w * d;
        }
    } else {
        const unsigned short* hb = (const unsigned short*)h;
        int k = r0;
        for (; k + 4 <= r1; k += 4) {
            int s0 = srcS[k], s1 = srcS[k + 1], s2 = srcS[k + 2], s3 = srcS[k + 3];
            float d0 = dis[s0], d1 = dis[s1], d2 = dis[s2], d3 = dis[s3];
            float4 a0 = tg71_u2f4(*(const ushort4*)&hb[(long)s0 * TG_D + fo]);
            float4 a1 = tg71_u2f4(*(const ushort4*)&hb[(long)s1 * TG_D + fo]);
            float4 a2 = tg71_u2f4(*(const ushort4*)&hb[(long)s2 * TG_D + fo]);
            float4 a3 = tg71_u2f4(*(const ushort4*)&hb[(long)s3 * TG_D + fo]);
            acc.x += a0.x * d0 + a1.x * d1 + a2.x * d2 + a3.x * d3;
            acc.y += a0.y * d0 + a1.y * d1 + a2.y * d2 + a3.y * d3;
            acc.z += a0.z * d0 + a1.z * d1 + a2.z * d2 + a3.z * d3;
            acc.w += a0.w * d0 + a1.w * d1 + a2.w * d2 + a3.w * d3;
        }
        for (; k < r1; ++k) {
            int s = srcS[k];
            float d = dis[s];
            float4 a = tg71_u2f4(*(const ushort4*)&hb[(long)s * TG_D + fo]);
            acc.x += a.x * d; acc.y += a.y * d; acc.z += a.z * d; acc.w += a.w * d;
        }
    }
    float dn = dis[n];
    acc.x *= dn; acc.y *= dn; acc.z *= dn; acc.w *= dn;
    *(ushort4*)&out[(long)n * TG_D + fo] = tg71_pack4(acc);
}

// ---- tiled GEMM: 128-node M-tile, N=64, K=256 (4 segments); bf16 LDS ----
// h0Mode: 0 = follow flags (model input x), 2 = always bf16.
__global__ __launch_bounds__(256) void tg71_gemm(
    const void* h0, int h0Mode, const unsigned short* g1, const unsigned short* g2,
    const unsigned short* g3, const void* W, const void* bias, const int* flags,
    unsigned short* yOut, int doHead, const void* Wc, const void* bc, void* outp) {
    __shared__ unsigned short sW[64 * 64];   // 8 KB: W K-segment bf16 (reused: Wc^T + bc)
    __shared__ unsigned short sH[128 * 68];  // 17.4 KB: h tile bf16 (reused for z)

    const int t  = threadIdx.x;
    const int jb = t & 7;             // 0..7  -> cols j0..j0+7
    const int mb = t >> 3;            // 0..31 -> nodes mb + 32*i
    const int j0 = jb * 8;
    const int fF = flags[1];
    const int h0F32 = (h0Mode == 2) ? 0 : fF;
    const long tile = (long)blockIdx.x * 128;

    float4 aLo[4], aHi[4];
#pragma unroll
    for (int i = 0; i < 4; ++i) {
        aLo[i] = float4{0.f, 0.f, 0.f, 0.f};
        aHi[i] = float4{0.f, 0.f, 0.f, 0.f};
    }

    for (int seg = 0; seg < 4; ++seg) {
        const int hf = (seg == 0) ? h0F32 : 0;
        const void* hs = (seg == 0) ? h0
                       : (seg == 1 ? (const void*)g1 : (seg == 2 ? (const void*)g2 : (const void*)g3));
        if (seg) __syncthreads();
        // stage W segment -> bf16 LDS
        for (int i = t * 4; i < 64 * 64; i += 1024) {
            ushort4 w4;
            if (fF) w4 = tg71_pack4(*(const float4*)((const float*)W + (long)seg * 4096 + i));
            else    w4 = *(const ushort4*)((const unsigned short*)W + (long)seg * 4096 + i);
            *(ushort4*)&sW[i] = w4;
        }
        // stage h tile -> bf16 LDS (pitch 68)
        for (int i = t * 4; i < 128 * 64; i += 1024) {
            int m = i >> 6, f = i & 63;
            long n = tile + m;
            ushort4 hv;
            if (n < TG_NN) {
                if (hf) hv = tg71_pack4(*(const float4*)((const float*)hs + n * TG_D + f));
                else    hv = *(const ushort4*)((const unsigned short*)hs + n * TG_D + f);
            } else hv = ushort4{0, 0, 0, 0};
            *(ushort4*)&sH[m * 68 + f] = hv;
        }
        __syncthreads();
        for (int fc = 0; fc < 64; fc += 4) {
            float4 hv[4];
#pragma unroll
            for (int i = 0; i < 4; ++i)
                hv[i] = tg71_u2f4(*(const ushort4*)&sH[(mb + 32 * i) * 68 + fc]);
#pragma unroll
            for (int ff = 0; ff < 4; ++ff) {
                float4 wLo = tg71_u2f4(*(const ushort4*)&sW[(fc + ff) * 64 + j0]);
                float4 wHi = tg71_u2f4(*(const ushort4*)&sW[(fc + ff) * 64 + j0 + 4]);
#pragma unroll
                for (int i = 0; i < 4; ++i) {
                    float hsv = tg71_f4c(hv[i], ff);
                    aLo[i].x += hsv * wLo.x; aLo[i].y += hsv * wLo.y;
                    aLo[i].z += hsv * wLo.z; aLo[i].w += hsv * wLo.w;
                    aHi[i].x += hsv * wHi.x; aHi[i].y += hsv * wHi.y;
                    aHi[i].z += hsv * wHi.z; aHi[i].w += hsv * wHi.w;
                }
            }
        }
    }

    // epilogue: bias + relu
    float4 bLo, bHi;
    bLo.x = tg71_ld(bias, j0 + 0, fF); bLo.y = tg71_ld(bias, j0 + 1, fF);
    bLo.z = tg71_ld(bias, j0 + 2, fF); bLo.w = tg71_ld(bias, j0 + 3, fF);
    bHi.x = tg71_ld(bias, j0 + 4, fF); bHi.y = tg71_ld(bias, j0 + 5, fF);
    bHi.z = tg71_ld(bias, j0 + 6, fF); bHi.w = tg71_ld(bias, j0 + 7, fF);
#pragma unroll
    for (int i = 0; i < 4; ++i) {
        aLo[i].x = fmaxf(aLo[i].x + bLo.x, 0.f); aLo[i].y = fmaxf(aLo[i].y + bLo.y, 0.f);
        aLo[i].z = fmaxf(aLo[i].z + bLo.z, 0.f); aLo[i].w = fmaxf(aLo[i].w + bLo.w, 0.f);
        aHi[i].x = fmaxf(aHi[i].x + bHi.x, 0.f); aHi[i].y = fmaxf(aHi[i].y + bHi.y, 0.f);
        aHi[i].z = fmaxf(aHi[i].z + bHi.z, 0.f); aHi[i].w = fmaxf(aHi[i].w + bHi.w, 0.f);
    }

    if (!doHead) {
#pragma unroll
        for (int i = 0; i < 4; ++i) {
            long n = tile + mb + 32 * i;
            if (n < TG_NN) {
                *(ushort4*)&yOut[n * TG_D + j0]     = tg71_pack4(aLo[i]);
                *(ushort4*)&yOut[n * TG_D + j0 + 4] = tg71_pack4(aHi[i]);
            }
        }
        return;
    }

    // fused head: park z (bf16) in sH, stage Wc^T (bf16) + bc in sW
    __syncthreads();
#pragma unroll
    for (int i = 0; i < 4; ++i) {
        *(ushort4*)&sH[(mb + 32 * i) * 68 + j0]     = tg71_pack4(aLo[i]);
        *(ushort4*)&sH[(mb + 32 * i) * 68 + j0 + 4] = tg71_pack4(aHi[i]);
    }
    for (int i = t; i < 64 * TG_NC; i += 256) {
        int f = i / TG_NC, c = i - f * TG_NC;
        sW[c * 68 + f] = fF ? tg71_f2b(((const float*)Wc)[i]) : ((const unsigned short*)Wc)[i];
    }
    if (t < TG_NC) sW[40 * 68 + t] = fF ? tg71_f2b(((const float*)bc)[t]) : ((const unsigned short*)bc)[t];
    __syncthreads();

    float hacc[4][5];
#pragma unroll
    for (int i = 0; i < 4; ++i)
#pragma unroll
        for (int q = 0; q < 5; ++q) hacc[i][q] = 0.f;
    for (int fc = 0; fc < 64; fc += 4) {
        float4 zv[4], wv[5];
#pragma unroll
        for (int i = 0; i < 4; ++i)
            zv[i] = tg71_u2f4(*(const ushort4*)&sH[(mb + 32 * i) * 68 + fc]);
#pragma unroll
        for (int q = 0; q < 5; ++q)
            wv[q] = tg71_u2f4(*(const ushort4*)&sW[(jb * 5 + q) * 68 + fc]);
#pragma unroll
        for (int i = 0; i < 4; ++i)
#pragma unroll
            for (int q = 0; q < 5; ++q)
                hacc[i][q] += zv[i].x * wv[q].x + zv[i].y * wv[q].y +
                              zv[i].z * wv[q].z + zv[i].w * wv[q].w;
    }
#pragma unroll
    for (int i = 0; i < 4; ++i) {
        long n = tile + mb + 32 * i;
        if (n < TG_NN) {
#pragma unroll
            for (int q = 0; q < 5; ++q) {
                int c = jb * 5 + q;
                tg71_st(outp, n * TG_NC + c, fF, hacc[i][q] + tg71_b2f(sW[40 * 68 + c]));
            }
        }
    }
}

extern "C" void kernel_launch(void* const* d_in, const int* in_sizes, int n_in,
                              void* d_out, int out_size, void* d_ws, size_t ws_size,
                              hipStream_t stream) {
    const void* x  = d_in[0];
    const int*  ei = (const int*)d_in[1];
    const void* W1 = d_in[2];
    const void* b1 = d_in[3];
    const void* W2 = d_in[4];
    const void* b2 = d_in[5];
    const void* Wc = d_in[6];
    const void* bc = d_in[7];

    // workspace layout (4-byte words); hop buffers bf16, base 16B-aligned
    int*   flags  = (int*)d_ws;                     // [16]
    int*   srcI   = flags + 16;                     // [NE]
    int*   dstI   = srcI + TG_NE;                   // [NE]
    int*   srcS   = dstI + TG_NE;                   // [NE]
    int*   cnt    = srcS + TG_NE;                   // [NN]
    float* dis    = (float*)(cnt + TG_NN);          // [NN]
    int*   rowptr = (int*)(dis + TG_NN);            // [NN+1]
    int*   fill   = rowptr + TG_NN + 1;             // [NN]
    int*   part   = fill + TG_NN;                   // [128]
    unsigned short* A = (unsigned short*)(((uintptr_t)(part + 128) + 15) & ~(uintptr_t)15);
    unsigned short* B = A + (long)TG_NN * TG_D;              // [NN*D] bf16
    unsigned short* C = B + (long)TG_NN * TG_D;              // [NN*D] bf16
    unsigned short* Y = C + (long)TG_NN * TG_D;              // [NN*D] bf16

    const int gE  = (TG_NE + TG_BT - 1) / TG_BT;
    const int gN  = (TG_NN + TG_BT - 1) / TG_BT;
    const int gP  = TG_NN / 4 * 64 / TG_BT;         // 6250: 4 nodes/wave
    const int gT  = (TG_NN + 127) / 128;            // 782 gemm tiles

    tg71_detect<<<1, 64, 0, stream>>>(ei, (const unsigned short*)W1, flags);

    // CSR build
    tg71_zero_i<<<gN, TG_BT, 0, stream>>>(cnt, TG_NN);
    tg71_edges<<<gE, TG_BT, 0, stream>>>(ei, flags, srcI, dstI, cnt);
    tg71_scan1<<<TG_NP, TG_BT, 0, stream>>>(cnt, rowptr, part, dis);
    tg71_scan2<<<1, 128, 0, stream>>>(part);
    tg71_scan3<<<gN, TG_BT, 0, stream>>>(rowptr, part, fill);
    for (int pass = 0; pass < 4; ++pass)
        tg71_scatter<<<gE, TG_BT, 0, stream>>>(srcI, dstI, fill, srcS, pass);

    // layer 1
    tg71_prop_x<<<gP, TG_BT, 0, stream>>>(rowptr, srcS, dis, x, flags, A);
    tg71_prop_b<<<gP, TG_BT, 0, stream>>>(rowptr, srcS, dis, A, B);
    tg71_prop_b<<<gP, TG_BT, 0, stream>>>(rowptr, srcS, dis, B, C);
    tg71_gemm<<<gT, TG_BT, 0, stream>>>(x, 0, A, B, C, W1, b1, flags,
                                        Y, 0, nullptr, nullptr, nullptr);

    // layer 2 + fused head (Y is bf16 -> h0Mode 2)
    tg71_prop_b<<<gP, TG_BT, 0, stream>>>(rowptr, srcS, dis, Y, A);
    tg71_prop_b<<<gP, TG_BT, 0, stream>>>(rowptr, srcS, dis, A, B);
    tg71_prop_b<<<gP, TG_BT, 0, stream>>>(rowptr, srcS, dis, B, C);
    tg71_gemm<<<gT, TG_BT, 0, stream>>>(Y, 2, A, B, C, W2, b2, flags,
                                        nullptr, 1, Wc, bc, d_out);
}

// Round 10
// 567.112 us; speedup vs baseline: 8.7987x; 1.1176x over previous
//
#include <hip/hip_runtime.h>
#include <hip/hip_bf16.h>
#include <stdint.h>

static constexpr int TG_NN = 100000;
static constexpr int TG_NE = 1200000;
static constexpr int TG_D  = 64;
static constexpr int TG_NC = 40;
static constexpr int TG_BT = 256;
static constexpr int TG_NP = (TG_NN + 1023) / 1024;  // scan blocks (98)

typedef __attribute__((ext_vector_type(8))) short tg71_s8;
typedef __attribute__((ext_vector_type(4))) float tg71_f4;

// ---- dtype helpers ----
__device__ __forceinline__ float tg71_b2f(unsigned short u) {
    return __uint_as_float(((unsigned int)u) << 16);
}
__device__ __forceinline__ unsigned short tg71_f2b(float v) {
    __hip_bfloat16 b = __float2bfloat16(v);  // RNE
    return __builtin_bit_cast(unsigned short, b);
}
__device__ __forceinline__ float tg71_ld(const void* p, long i, int isF32) {
    if (isF32) return ((const float*)p)[i];
    return tg71_b2f(((const unsigned short*)p)[i]);
}
__device__ __forceinline__ void tg71_st(void* p, long i, int isF32, float v) {
    if (isF32) ((float*)p)[i] = v;
    else ((unsigned short*)p)[i] = tg71_f2b(v);
}
__device__ __forceinline__ float4 tg71_u2f4(ushort4 u) {
    return float4{tg71_b2f(u.x), tg71_b2f(u.y), tg71_b2f(u.z), tg71_b2f(u.w)};
}
__device__ __forceinline__ ushort4 tg71_pack4(float4 v) {
    return ushort4{tg71_f2b(v.x), tg71_f2b(v.y), tg71_f2b(v.z), tg71_f2b(v.w)};
}

// flags[0] = edge_index is int64 ; flags[1] = float tensors are fp32
__global__ void tg71_detect(const int* ei, const unsigned short* w1bits, int* flags) {
    int lane = threadIdx.x;  // 64 threads
    int hi = ei[2 * lane + 1];
    unsigned long long bi = __ballot(hi != 0);
    float mx = 0.0f;
    for (int k = lane; k < 2048; k += 64) {
        float v = fabsf(tg71_b2f(w1bits[k]));
        if (!(v == v)) v = 1e30f;
        mx = fmaxf(mx, v);
    }
    unsigned long long bf = __ballot(mx > 1e4f);
    if (lane == 0) { flags[0] = (bi == 0ULL) ? 1 : 0; flags[1] = (bf != 0ULL) ? 1 : 0; }
}

// Kept for pipeline symbol validation; not launched (head writes all outputs).
extern "C" __global__ void TAGModel_71227737636876_kernel(void* out, const int* flags) {
    long i = (long)blockIdx.x * blockDim.x + threadIdx.x;
    if (i < (long)TG_NN * TG_NC) tg71_st(out, i, flags[1], 123.0f);
}

__global__ void tg71_zero_i(int* p, int n) {
    int i = blockIdx.x * blockDim.x + threadIdx.x;
    if (i < n) p[i] = 0;
}

// Pre-transpose W [256,64] -> Wt [64,256] bf16 (k-contiguous for MFMA B-frags)
__global__ void tg71_wt(const void* W, const int* flags, unsigned short* Wt) {
    int i = blockIdx.x * blockDim.x + threadIdx.x;
    if (i >= 256 * 64) return;
    int k = i >> 6, n = i & 63;
    Wt[n * 256 + k] = flags[1] ? tg71_f2b(((const float*)W)[i]) : ((const unsigned short*)W)[i];
}

// edge decode + degree histogram fused (cnt must be zeroed first)
__global__ void tg71_edges(const int* ei, const int* flags, int* srcI, int* dstI, int* cnt) {
    int e = blockIdx.x * blockDim.x + threadIdx.x;
    if (e >= TG_NE) return;
    int s, d;
    if (flags[0]) { s = ei[2 * e]; d = ei[2 * TG_NE + 2 * e]; }
    else          { s = ei[e];     d = ei[TG_NE + e]; }
    srcI[e] = s;
    dstI[e] = d;
    atomicAdd(cnt + d, 1);
}

// ---- hierarchical exclusive scan of cnt[NN] -> rowptr[NN+1]; also emits dis ----
__global__ void tg71_scan1(const int* cnt, int* rowptr, int* part, float* dis) {
    __shared__ int sh[256];
    int t = threadIdx.x;
    int base = blockIdx.x * 1024 + t * 4;
    int v0 = base + 0 < TG_NN ? cnt[base + 0] : 0;
    int v1 = base + 1 < TG_NN ? cnt[base + 1] : 0;
    int v2 = base + 2 < TG_NN ? cnt[base + 2] : 0;
    int v3 = base + 3 < TG_NN ? cnt[base + 3] : 0;
    if (base + 0 < TG_NN) dis[base + 0] = v0 > 0 ? rsqrtf((float)v0) : 0.0f;
    if (base + 1 < TG_NN) dis[base + 1] = v1 > 0 ? rsqrtf((float)v1) : 0.0f;
    if (base + 2 < TG_NN) dis[base + 2] = v2 > 0 ? rsqrtf((float)v2) : 0.0f;
    if (base + 3 < TG_NN) dis[base + 3] = v3 > 0 ? rsqrtf((float)v3) : 0.0f;
    int p1 = v0, p2 = v0 + v1, p3 = v0 + v1 + v2, sum = p3 + v3;
    sh[t] = sum;
    __syncthreads();
    for (int off = 1; off < 256; off <<= 1) {
        int x = (t >= off) ? sh[t - off] : 0;
        __syncthreads();
        if (t >= off) sh[t] += x;
        __syncthreads();
    }
    int ex = sh[t] - sum;
    if (base + 0 < TG_NN) rowptr[base + 0] = ex;
    if (base + 1 < TG_NN) rowptr[base + 1] = ex + p1;
    if (base + 2 < TG_NN) rowptr[base + 2] = ex + p2;
    if (base + 3 < TG_NN) rowptr[base + 3] = ex + p3;
    if (t == 255) part[blockIdx.x] = sh[255];
}

__global__ void tg71_scan2(int* part) {
    __shared__ int sh[128];
    int t = threadIdx.x;
    int v = t < TG_NP ? part[t] : 0;
    sh[t] = v;
    __syncthreads();
    for (int off = 1; off < 128; off <<= 1) {
        int x = (t >= off) ? sh[t - off] : 0;
        __syncthreads();
        if (t >= off) sh[t] += x;
        __syncthreads();
    }
    if (t < TG_NP) part[t] = sh[t] - v;
}

__global__ void tg71_scan3(int* rowptr, const int* part, int* fill) {
    int i = blockIdx.x * blockDim.x + threadIdx.x;
    if (i < TG_NN) {
        int r = rowptr[i] + part[i >> 10];
        rowptr[i] = r;
        fill[i] = r;
    }
    if (i == 0) rowptr[TG_NN] = TG_NE;
}

// Windowed CSR scatter: pass p handles dst in [p*32768, (p+1)*32768).
__global__ void tg71_scatter(const int* __restrict__ srcI, const int* __restrict__ dstI,
                             int* fill, int* srcS, int pass) {
    int e = blockIdx.x * blockDim.x + threadIdx.x;
    if (e >= TG_NE) return;
    int d = dstI[e];
    if ((d >> 15) != pass) return;
    int pos = atomicAdd(fill + d, 1);
    srcS[pos] = srcI[e];
}

// ---- propagation: h'[n] = bf16( dis[n] * sum_{src->n} dis[src]*h[src] ) ----
// 4 nodes per wave (16-lane groups, 4 features/lane).

__global__ void tg71_prop_b(const int* __restrict__ rowptr, const int* __restrict__ srcS,
                            const float* __restrict__ dis, const unsigned short* __restrict__ h,
                            unsigned short* __restrict__ out) {
    int gid = blockIdx.x * blockDim.x + threadIdx.x;
    int wid = gid >> 6, lane = gid & 63;
    int g = lane >> 4, li = lane & 15;
    int n = wid * 4 + g;
    int r0 = rowptr[n], r1 = rowptr[n + 1];
    float4 acc = float4{0.f, 0.f, 0.f, 0.f};
    long fo = (long)li * 4;
    int k = r0;
    for (; k + 4 <= r1; k += 4) {
        int s0 = srcS[k], s1 = srcS[k + 1], s2 = srcS[k + 2], s3 = srcS[k + 3];
        float d0 = dis[s0], d1 = dis[s1], d2 = dis[s2], d3 = dis[s3];
        float4 a0 = tg71_u2f4(*(const ushort4*)&h[(long)s0 * TG_D + fo]);
        float4 a1 = tg71_u2f4(*(const ushort4*)&h[(long)s1 * TG_D + fo]);
        float4 a2 = tg71_u2f4(*(const ushort4*)&h[(long)s2 * TG_D + fo]);
        float4 a3 = tg71_u2f4(*(const ushort4*)&h[(long)s3 * TG_D + fo]);
        acc.x += a0.x * d0 + a1.x * d1 + a2.x * d2 + a3.x * d3;
        acc.y += a0.y * d0 + a1.y * d1 + a2.y * d2 + a3.y * d3;
        acc.z += a0.z * d0 + a1.z * d1 + a2.z * d2 + a3.z * d3;
        acc.w += a0.w * d0 + a1.w * d1 + a2.w * d2 + a3.w * d3;
    }
    for (; k < r1; ++k) {
        int s = srcS[k];
        float d = dis[s];
        float4 a = tg71_u2f4(*(const ushort4*)&h[(long)s * TG_D + fo]);
        acc.x += a.x * d; acc.y += a.y * d; acc.z += a.z * d; acc.w += a.w * d;
    }
    float dn = dis[n];
    acc.x *= dn; acc.y *= dn; acc.z *= dn; acc.w *= dn;
    *(ushort4*)&out[(long)n * TG_D + fo] = tg71_pack4(acc);
}

__global__ void tg71_prop_x(const int* __restrict__ rowptr, const int* __restrict__ srcS,
                            const float* __restrict__ dis, const void* __restrict__ h,
                            const int* flags, unsigned short* __restrict__ out) {
    int gid = blockIdx.x * blockDim.x + threadIdx.x;
    int wid = gid >> 6, lane = gid & 63;
    int g = lane >> 4, li = lane & 15;
    int n = wid * 4 + g;
    int r0 = rowptr[n], r1 = rowptr[n + 1];
    float4 acc = float4{0.f, 0.f, 0.f, 0.f};
    long fo = (long)li * 4;
    if (flags[1]) {
        const float* hf = (const float*)h;
        for (int k = r0; k < r1; ++k) {
            int s = srcS[k];
            float d = dis[s];
            float4 a = *(const float4*)&hf[(long)s * TG_D + fo];
            acc.x += a.x * d; acc.y += a.y * d; acc.z += a.z * d; acc.w += a.w * d;
        }
    } else {
        const unsigned short* hb = (const unsigned short*)h;
        int k = r0;
        for (; k + 4 <= r1; k += 4) {
            int s0 = srcS[k], s1 = srcS[k + 1], s2 = srcS[k + 2], s3 = srcS[k + 3];
            float d0 = dis[s0], d1 = dis[s1], d2 = dis[s2], d3 = dis[s3];
            float4 a0 = tg71_u2f4(*(const ushort4*)&hb[(long)s0 * TG_D + fo]);
            float4 a1 = tg71_u2f4(*(const ushort4*)&hb[(long)s1 * TG_D + fo]);
            float4 a2 = tg71_u2f4(*(const ushort4*)&hb[(long)s2 * TG_D + fo]);
            float4 a3 = tg71_u2f4(*(const ushort4*)&hb[(long)s3 * TG_D + fo]);
            acc.x += a0.x * d0 + a1.x * d1 + a2.x * d2 + a3.x * d3;
            acc.y += a0.y * d0 + a1.y * d1 + a2.y * d2 + a3.y * d3;
            acc.z += a0.z * d0 + a1.z * d1 + a2.z * d2 + a3.z * d3;
            acc.w += a0.w * d0 + a1.w * d1 + a2.w * d2 + a3.w * d3;
        }
        for (; k < r1; ++k) {
            int s = srcS[k];
            float d = dis[s];
            float4 a = tg71_u2f4(*(const ushort4*)&hb[(long)s * TG_D + fo]);
            acc.x += a.x * d; acc.y += a.y * d; acc.z += a.z * d; acc.w += a.w * d;
        }
    }
    float dn = dis[n];
    acc.x *= dn; acc.y *= dn; acc.z *= dn; acc.w *= dn;
    *(ushort4*)&out[(long)n * TG_D + fo] = tg71_pack4(acc);
}

// ---- MFMA tiled GEMM: M-tile 128, N=64, K=256 (4 segments of 64) ----
// Fragment layouts (HW-verified, learn_hip m89/m120):
//   A: row = lane&15, k = (lane>>4)*8 + j   (8 contiguous bf16 -> ds_read_b128)
//   B: col = lane&15, k = (lane>>4)*8 + j   (needs k-contiguous W -> pre-transposed Wt)
//   D: col = lane&15, row = (lane>>4)*4 + reg
// h0Mode: 0 = follow flags (model input x), 2 = always bf16.
__global__ __launch_bounds__(256) void tg71_gemm(
    const void* h0, int h0Mode, const unsigned short* g1, const unsigned short* g2,
    const unsigned short* g3, const unsigned short* Wt, const void* bias, const int* flags,
    unsigned short* yOut, int doHead, const void* Wc, const void* bc, void* outp) {
    __shared__ __align__(16) unsigned short sA[128 * 72];  // 18.4 KB hop tile (pitch 72)
    __shared__ __align__(16) unsigned short sB[64 * 72];   // 9.2 KB Wt slice (pitch 72)

    const int t    = threadIdx.x;
    const int wave = t >> 6;
    const int lane = t & 63;
    const int quad = lane >> 4;
    const int lr   = lane & 15;
    const int fF   = flags[1];
    const int h0F32 = (h0Mode == 2) ? 0 : fF;
    const long tile = (long)blockIdx.x * 128;

    tg71_f4 acc[2][4];
#pragma unroll
    for (int mt = 0; mt < 2; ++mt)
#pragma unroll
        for (int nt = 0; nt < 4; ++nt) acc[mt][nt] = tg71_f4{0.f, 0.f, 0.f, 0.f};

    for (int seg = 0; seg < 4; ++seg) {
        const int hf = (seg == 0) ? h0F32 : 0;
        const void* hs = (seg == 0) ? h0
                       : (seg == 1 ? (const void*)g1 : (seg == 2 ? (const void*)g2 : (const void*)g3));
        if (seg) __syncthreads();
        // stage Wt slice: sB[n*72 + kk] = Wt[n*256 + seg*64 + kk]
        for (int c = t; c < 1024; c += 256) {
            int n = c >> 4, k4 = (c & 15) * 4;
            *(ushort4*)&sB[n * 72 + k4] = *(const ushort4*)&Wt[n * 256 + seg * 64 + k4];
        }
        // stage hop tile: sA[m*72 + f]
        for (int c = t; c < 2048; c += 256) {
            int m = c >> 4, f4 = (c & 15) * 4;
            long n = tile + m;
            ushort4 hv = ushort4{0, 0, 0, 0};
            if (n < TG_NN) {
                if (hf) hv = tg71_pack4(*(const float4*)((const float*)hs + n * TG_D + f4));
                else    hv = *(const ushort4*)((const unsigned short*)hs + n * TG_D + f4);
            }
            *(ushort4*)&sA[m * 72 + f4] = hv;
        }
        __syncthreads();
#pragma unroll
        for (int ks = 0; ks < 2; ++ks) {
            int ko = ks * 32 + quad * 8;
            tg71_s8 a0 = *(const tg71_s8*)&sA[(wave * 32 + lr) * 72 + ko];
            tg71_s8 a1 = *(const tg71_s8*)&sA[(wave * 32 + 16 + lr) * 72 + ko];
            tg71_s8 b0 = *(const tg71_s8*)&sB[(lr) * 72 + ko];
            tg71_s8 b1 = *(const tg71_s8*)&sB[(16 + lr) * 72 + ko];
            tg71_s8 b2 = *(const tg71_s8*)&sB[(32 + lr) * 72 + ko];
            tg71_s8 b3 = *(const tg71_s8*)&sB[(48 + lr) * 72 + ko];
            acc[0][0] = __builtin_amdgcn_mfma_f32_16x16x32_bf16(a0, b0, acc[0][0], 0, 0, 0);
            acc[0][1] = __builtin_amdgcn_mfma_f32_16x16x32_bf16(a0, b1, acc[0][1], 0, 0, 0);
            acc[0][2] = __builtin_amdgcn_mfma_f32_16x16x32_bf16(a0, b2, acc[0][2], 0, 0, 0);
            acc[0][3] = __builtin_amdgcn_mfma_f32_16x16x32_bf16(a0, b3, acc[0][3], 0, 0, 0);
            acc[1][0] = __builtin_amdgcn_mfma_f32_16x16x32_bf16(a1, b0, acc[1][0], 0, 0, 0);
            acc[1][1] = __builtin_amdgcn_mfma_f32_16x16x32_bf16(a1, b1, acc[1][1], 0, 0, 0);
            acc[1][2] = __builtin_amdgcn_mfma_f32_16x16x32_bf16(a1, b2, acc[1][2], 0, 0, 0);
            acc[1][3] = __builtin_amdgcn_mfma_f32_16x16x32_bf16(a1, b3, acc[1][3], 0, 0, 0);
        }
    }

    // bias per column (nt*16 + lr)
    float bv[4];
#pragma unroll
    for (int nt = 0; nt < 4; ++nt) bv[nt] = tg71_ld(bias, nt * 16 + lr, fF);

    __syncthreads();  // all MFMA LDS reads done before reuse

    const int zp = doHead ? 68 : 64;  // z-park pitch (68 for head layout)
#pragma unroll
    for (int mt = 0; mt < 2; ++mt) {
#pragma unroll
        for (int r = 0; r < 4; ++r) {
            int ml = wave * 32 + mt * 16 + quad * 4 + r;
#pragma unroll
            for (int nt = 0; nt < 4; ++nt) {
                float v = fmaxf(acc[mt][nt][r] + bv[nt], 0.f);
                sA[ml * zp + nt * 16 + lr] = tg71_f2b(v);
            }
        }
    }

    if (!doHead) {
        __syncthreads();
        for (int c = t; c < 2048; c += 256) {
            int m = c >> 4, f4 = (c & 15) * 4;
            if (tile + m < TG_NN)
                *(ushort4*)&yOut[(tile + m) * TG_D + f4] = *(const ushort4*)&sA[m * 64 + f4];
        }
        return;
    }

    // fused head: z is parked in sA (pitch 68); stage Wc^T (bf16) + bc in sB
    for (int i = t; i < 64 * TG_NC; i += 256) {
        int f = i / TG_NC, c = i - f * TG_NC;
        sB[c * 68 + f] = fF ? tg71_f2b(((const float*)Wc)[i]) : ((const unsigned short*)Wc)[i];
    }
    if (t < TG_NC) sB[40 * 68 + t] = fF ? tg71_f2b(((const float*)bc)[t]) : ((const unsigned short*)bc)[t];
    __syncthreads();

    const int jb = t & 7;   // 0..7 -> cols jb*5..jb*5+4
    const int mb = t >> 3;  // 0..31 -> nodes mb + 32*i
    float hacc[4][5];
#pragma unroll
    for (int i = 0; i < 4; ++i)
#pragma unroll
        for (int q = 0; q < 5; ++q) hacc[i][q] = 0.f;
    for (int fc = 0; fc < 64; fc += 4) {
        float4 zv[4], wv[5];
#pragma unroll
        for (int i = 0; i < 4; ++i)
            zv[i] = tg71_u2f4(*(const ushort4*)&sA[(mb + 32 * i) * 68 + fc]);
#pragma unroll
        for (int q = 0; q < 5; ++q)
            wv[q] = tg71_u2f4(*(const ushort4*)&sB[(jb * 5 + q) * 68 + fc]);
#pragma unroll
        for (int i = 0; i < 4; ++i)
#pragma unroll
            for (int q = 0; q < 5; ++q)
                hacc[i][q] += zv[i].x * wv[q].x + zv[i].y * wv[q].y +
                              zv[i].z * wv[q].z + zv[i].w * wv[q].w;
    }
#pragma unroll
    for (int i = 0; i < 4; ++i) {
        long n = tile + mb + 32 * i;
        if (n < TG_NN) {
#pragma unroll
            for (int q = 0; q < 5; ++q) {
                int c = jb * 5 + q;
                tg71_st(outp, n * TG_NC + c, fF, hacc[i][q] + tg71_b2f(sB[40 * 68 + c]));
            }
        }
    }
}

extern "C" void kernel_launch(void* const* d_in, const int* in_sizes, int n_in,
                              void* d_out, int out_size, void* d_ws, size_t ws_size,
                              hipStream_t stream) {
    const void* x  = d_in[0];
    const int*  ei = (const int*)d_in[1];
    const void* W1 = d_in[2];
    const void* b1 = d_in[3];
    const void* W2 = d_in[4];
    const void* b2 = d_in[5];
    const void* Wc = d_in[6];
    const void* bc = d_in[7];

    // workspace layout (4-byte words); hop buffers bf16, base 16B-aligned
    int*   flags  = (int*)d_ws;                     // [16]
    int*   srcI   = flags + 16;                     // [NE]
    int*   dstI   = srcI + TG_NE;                   // [NE]
    int*   srcS   = dstI + TG_NE;                   // [NE]
    int*   cnt    = srcS + TG_NE;                   // [NN]
    float* dis    = (float*)(cnt + TG_NN);          // [NN]
    int*   rowptr = (int*)(dis + TG_NN);            // [NN+1]
    int*   fill   = rowptr + TG_NN + 1;             // [NN]
    int*   part   = fill + TG_NN;                   // [128]
    unsigned short* A = (unsigned short*)(((uintptr_t)(part + 128) + 15) & ~(uintptr_t)15);
    unsigned short* B = A + (long)TG_NN * TG_D;              // [NN*D] bf16
    unsigned short* C = B + (long)TG_NN * TG_D;              // [NN*D] bf16
    unsigned short* Y = C + (long)TG_NN * TG_D;              // [NN*D] bf16
    unsigned short* Wt1 = Y + (long)TG_NN * TG_D;            // [64*256] bf16
    unsigned short* Wt2 = Wt1 + 64 * 256;                    // [64*256] bf16

    const int gE  = (TG_NE + TG_BT - 1) / TG_BT;
    const int gN  = (TG_NN + TG_BT - 1) / TG_BT;
    const int gP  = TG_NN / 4 * 64 / TG_BT;         // 6250: 4 nodes/wave
    const int gT  = (TG_NN + 127) / 128;            // 782 gemm tiles

    tg71_detect<<<1, 64, 0, stream>>>(ei, (const unsigned short*)W1, flags);
    tg71_wt<<<64, TG_BT, 0, stream>>>(W1, flags, Wt1);
    tg71_wt<<<64, TG_BT, 0, stream>>>(W2, flags, Wt2);

    // CSR build
    tg71_zero_i<<<gN, TG_BT, 0, stream>>>(cnt, TG_NN);
    tg71_edges<<<gE, TG_BT, 0, stream>>>(ei, flags, srcI, dstI, cnt);
    tg71_scan1<<<TG_NP, TG_BT, 0, stream>>>(cnt, rowptr, part, dis);
    tg71_scan2<<<1, 128, 0, stream>>>(part);
    tg71_scan3<<<gN, TG_BT, 0, stream>>>(rowptr, part, fill);
    for (int pass = 0; pass < 4; ++pass)
        tg71_scatter<<<gE, TG_BT, 0, stream>>>(srcI, dstI, fill, srcS, pass);

    // layer 1
    tg71_prop_x<<<gP, TG_BT, 0, stream>>>(rowptr, srcS, dis, x, flags, A);
    tg71_prop_b<<<gP, TG_BT, 0, stream>>>(rowptr, srcS, dis, A, B);
    tg71_prop_b<<<gP, TG_BT, 0, stream>>>(rowptr, srcS, dis, B, C);
    tg71_gemm<<<gT, TG_BT, 0, stream>>>(x, 0, A, B, C, Wt1, b1, flags,
                                        Y, 0, nullptr, nullptr, nullptr);

    // layer 2 + fused head (Y is bf16 -> h0Mode 2)
    tg71_prop_b<<<gP, TG_BT, 0, stream>>>(rowptr, srcS, dis, Y, A);
    tg71_prop_b<<<gP, TG_BT, 0, stream>>>(rowptr, srcS, dis, A, B);
    tg71_prop_b<<<gP, TG_BT, 0, stream>>>(rowptr, srcS, dis, B, C);
    tg71_gemm<<<gT, TG_BT, 0, stream>>>(Y, 2, A, B, C, Wt2, b2, flags,
                                        nullptr, 1, Wc, bc, d_out);
}

// Round 11
// 563.094 us; speedup vs baseline: 8.8615x; 1.0071x over previous
//
#include <hip/hip_runtime.h>
#include <hip/hip_bf16.h>
#include <stdint.h>

static constexpr int TG_NN = 100000;
static constexpr int TG_NE = 1200000;
static constexpr int TG_D  = 64;
static constexpr int TG_NC = 40;
static constexpr int TG_BT = 256;
static constexpr int TG_NP = (TG_NN + 1023) / 1024;  // scan blocks (98)

typedef __attribute__((ext_vector_type(8))) short tg71_s8;
typedef __attribute__((ext_vector_type(4))) float tg71_f4;

// ---- dtype helpers ----
__device__ __forceinline__ float tg71_b2f(unsigned short u) {
    return __uint_as_float(((unsigned int)u) << 16);
}
__device__ __forceinline__ unsigned short tg71_f2b(float v) {
    __hip_bfloat16 b = __float2bfloat16(v);  // RNE
    return __builtin_bit_cast(unsigned short, b);
}
__device__ __forceinline__ float tg71_ld(const void* p, long i, int isF32) {
    if (isF32) return ((const float*)p)[i];
    return tg71_b2f(((const unsigned short*)p)[i]);
}
__device__ __forceinline__ void tg71_st(void* p, long i, int isF32, float v) {
    if (isF32) ((float*)p)[i] = v;
    else ((unsigned short*)p)[i] = tg71_f2b(v);
}
__device__ __forceinline__ float4 tg71_u2f4(ushort4 u) {
    return float4{tg71_b2f(u.x), tg71_b2f(u.y), tg71_b2f(u.z), tg71_b2f(u.w)};
}
__device__ __forceinline__ float4 tg71_ld4(const void* p, long i, int isF32) {
    if (isF32) return *(const float4*)((const float*)p + i);
    return tg71_u2f4(*(const ushort4*)((const unsigned short*)p + i));
}
__device__ __forceinline__ ushort4 tg71_pack4(float4 v) {
    return ushort4{tg71_f2b(v.x), tg71_f2b(v.y), tg71_f2b(v.z), tg71_f2b(v.w)};
}

// flags[0] = edge_index is int64 ; flags[1] = float tensors are fp32
__global__ void tg71_detect(const int* ei, const unsigned short* w1bits, int* flags) {
    int lane = threadIdx.x;  // 64 threads
    int hi = ei[2 * lane + 1];
    unsigned long long bi = __ballot(hi != 0);
    float mx = 0.0f;
    for (int k = lane; k < 2048; k += 64) {
        float v = fabsf(tg71_b2f(w1bits[k]));
        if (!(v == v)) v = 1e30f;
        mx = fmaxf(mx, v);
    }
    unsigned long long bf = __ballot(mx > 1e4f);
    if (lane == 0) { flags[0] = (bi == 0ULL) ? 1 : 0; flags[1] = (bf != 0ULL) ? 1 : 0; }
}

// Kept for pipeline symbol validation; not launched (head writes all outputs).
extern "C" __global__ void TAGModel_71227737636876_kernel(void* out, const int* flags) {
    long i = (long)blockIdx.x * blockDim.x + threadIdx.x;
    if (i < (long)TG_NN * TG_NC) tg71_st(out, i, flags[1], 123.0f);
}

__global__ void tg71_zero_i(int* p, int n) {
    int i = blockIdx.x * blockDim.x + threadIdx.x;
    if (i < n) p[i] = 0;
}

// Pre-transpose W [256,64] -> Wt [64,256] bf16 (k-contiguous for MFMA B-frags)
__global__ void tg71_wt(const void* W, const int* flags, unsigned short* Wt) {
    int i = blockIdx.x * blockDim.x + threadIdx.x;
    if (i >= 256 * 64) return;
    int k = i >> 6, n = i & 63;
    Wt[n * 256 + k] = flags[1] ? tg71_f2b(((const float*)W)[i]) : ((const unsigned short*)W)[i];
}

// edge decode + degree histogram fused (cnt must be zeroed first)
__global__ void tg71_edges(const int* ei, const int* flags, int* srcI, int* dstI, int* cnt) {
    int e = blockIdx.x * blockDim.x + threadIdx.x;
    if (e >= TG_NE) return;
    int s, d;
    if (flags[0]) { s = ei[2 * e]; d = ei[2 * TG_NE + 2 * e]; }
    else          { s = ei[e];     d = ei[TG_NE + e]; }
    srcI[e] = s;
    dstI[e] = d;
    atomicAdd(cnt + d, 1);
}

// ---- hierarchical exclusive scan of cnt[NN] -> rowptr[NN+1]; also emits dis ----
__global__ void tg71_scan1(const int* cnt, int* rowptr, int* part, float* dis) {
    __shared__ int sh[256];
    int t = threadIdx.x;
    int base = blockIdx.x * 1024 + t * 4;
    int v0 = base + 0 < TG_NN ? cnt[base + 0] : 0;
    int v1 = base + 1 < TG_NN ? cnt[base + 1] : 0;
    int v2 = base + 2 < TG_NN ? cnt[base + 2] : 0;
    int v3 = base + 3 < TG_NN ? cnt[base + 3] : 0;
    if (base + 0 < TG_NN) dis[base + 0] = v0 > 0 ? rsqrtf((float)v0) : 0.0f;
    if (base + 1 < TG_NN) dis[base + 1] = v1 > 0 ? rsqrtf((float)v1) : 0.0f;
    if (base + 2 < TG_NN) dis[base + 2] = v2 > 0 ? rsqrtf((float)v2) : 0.0f;
    if (base + 3 < TG_NN) dis[base + 3] = v3 > 0 ? rsqrtf((float)v3) : 0.0f;
    int p1 = v0, p2 = v0 + v1, p3 = v0 + v1 + v2, sum = p3 + v3;
    sh[t] = sum;
    __syncthreads();
    for (int off = 1; off < 256; off <<= 1) {
        int x = (t >= off) ? sh[t - off] : 0;
        __syncthreads();
        if (t >= off) sh[t] += x;
        __syncthreads();
    }
    int ex = sh[t] - sum;
    if (base + 0 < TG_NN) rowptr[base + 0] = ex;
    if (base + 1 < TG_NN) rowptr[base + 1] = ex + p1;
    if (base + 2 < TG_NN) rowptr[base + 2] = ex + p2;
    if (base + 3 < TG_NN) rowptr[base + 3] = ex + p3;
    if (t == 255) part[blockIdx.x] = sh[255];
}

__global__ void tg71_scan2(int* part) {
    __shared__ int sh[128];
    int t = threadIdx.x;
    int v = t < TG_NP ? part[t] : 0;
    sh[t] = v;
    __syncthreads();
    for (int off = 1; off < 128; off <<= 1) {
        int x = (t >= off) ? sh[t - off] : 0;
        __syncthreads();
        if (t >= off) sh[t] += x;
        __syncthreads();
    }
    if (t < TG_NP) part[t] = sh[t] - v;
}

__global__ void tg71_scan3(int* rowptr, const int* part, int* fill) {
    int i = blockIdx.x * blockDim.x + threadIdx.x;
    if (i < TG_NN) {
        int r = rowptr[i] + part[i >> 10];
        rowptr[i] = r;
        fill[i] = r;
    }
    if (i == 0) rowptr[TG_NN] = TG_NE;
}

// Windowed CSR scatter: pass p handles dst in [p*32768, (p+1)*32768).
__global__ void tg71_scatter(const int* __restrict__ srcI, const int* __restrict__ dstI,
                             int* fill, int* srcS, int pass) {
    int e = blockIdx.x * blockDim.x + threadIdx.x;
    if (e >= TG_NE) return;
    int d = dstI[e];
    if ((d >> 15) != pass) return;
    int pos = atomicAdd(fill + d, 1);
    srcS[pos] = srcI[e];
}

// g0 = dis ⊙ x  (bf16 out; x fp32 or bf16 per flags)
__global__ void tg71_gx(const void* x, const int* flags, const float* __restrict__ dis,
                        unsigned short* __restrict__ g) {
    int tid = blockIdx.x * blockDim.x + threadIdx.x;
    long i4 = (long)tid * 4;
    if (i4 >= (long)TG_NN * TG_D) return;
    int n = (int)(i4 >> 6);
    float d = dis[n];
    float4 v = tg71_ld4(x, i4, flags[1]);
    v.x *= d; v.y *= d; v.z *= d; v.w *= d;
    *(ushort4*)&g[i4] = tg71_pack4(v);
}

// ---- propagation on pre-scaled hops: h'[n] = dis[n]*Σ g[s]; g'[n] = dis[n]*h'[n] ----
// 4 nodes per wave (16-lane groups, 4 features/lane); no per-edge dis load.
__global__ void tg71_prop_g(const int* __restrict__ rowptr, const int* __restrict__ srcS,
                            const float* __restrict__ dis, const unsigned short* __restrict__ g,
                            unsigned short* __restrict__ hOut,
                            unsigned short* __restrict__ gOut, int writeG) {
    int gid = blockIdx.x * blockDim.x + threadIdx.x;
    int wid = gid >> 6, lane = gid & 63;
    int grp = lane >> 4, li = lane & 15;
    int n = wid * 4 + grp;
    int r0 = rowptr[n], r1 = rowptr[n + 1];
    float4 acc = float4{0.f, 0.f, 0.f, 0.f};
    long fo = (long)li * 4;
    int k = r0;
    for (; k + 8 <= r1; k += 8) {
        int s0 = srcS[k],     s1 = srcS[k + 1], s2 = srcS[k + 2], s3 = srcS[k + 3];
        int s4 = srcS[k + 4], s5 = srcS[k + 5], s6 = srcS[k + 6], s7 = srcS[k + 7];
        float4 a0 = tg71_u2f4(*(const ushort4*)&g[(long)s0 * TG_D + fo]);
        float4 a1 = tg71_u2f4(*(const ushort4*)&g[(long)s1 * TG_D + fo]);
        float4 a2 = tg71_u2f4(*(const ushort4*)&g[(long)s2 * TG_D + fo]);
        float4 a3 = tg71_u2f4(*(const ushort4*)&g[(long)s3 * TG_D + fo]);
        float4 a4 = tg71_u2f4(*(const ushort4*)&g[(long)s4 * TG_D + fo]);
        float4 a5 = tg71_u2f4(*(const ushort4*)&g[(long)s5 * TG_D + fo]);
        float4 a6 = tg71_u2f4(*(const ushort4*)&g[(long)s6 * TG_D + fo]);
        float4 a7 = tg71_u2f4(*(const ushort4*)&g[(long)s7 * TG_D + fo]);
        acc.x += ((a0.x + a1.x) + (a2.x + a3.x)) + ((a4.x + a5.x) + (a6.x + a7.x));
        acc.y += ((a0.y + a1.y) + (a2.y + a3.y)) + ((a4.y + a5.y) + (a6.y + a7.y));
        acc.z += ((a0.z + a1.z) + (a2.z + a3.z)) + ((a4.z + a5.z) + (a6.z + a7.z));
        acc.w += ((a0.w + a1.w) + (a2.w + a3.w)) + ((a4.w + a5.w) + (a6.w + a7.w));
    }
    for (; k + 4 <= r1; k += 4) {
        int s0 = srcS[k], s1 = srcS[k + 1], s2 = srcS[k + 2], s3 = srcS[k + 3];
        float4 a0 = tg71_u2f4(*(const ushort4*)&g[(long)s0 * TG_D + fo]);
        float4 a1 = tg71_u2f4(*(const ushort4*)&g[(long)s1 * TG_D + fo]);
        float4 a2 = tg71_u2f4(*(const ushort4*)&g[(long)s2 * TG_D + fo]);
        float4 a3 = tg71_u2f4(*(const ushort4*)&g[(long)s3 * TG_D + fo]);
        acc.x += (a0.x + a1.x) + (a2.x + a3.x);
        acc.y += (a0.y + a1.y) + (a2.y + a3.y);
        acc.z += (a0.z + a1.z) + (a2.z + a3.z);
        acc.w += (a0.w + a1.w) + (a2.w + a3.w);
    }
    for (; k < r1; ++k) {
        int s = srcS[k];
        float4 a = tg71_u2f4(*(const ushort4*)&g[(long)s * TG_D + fo]);
        acc.x += a.x; acc.y += a.y; acc.z += a.z; acc.w += a.w;
    }
    float dn = dis[n];
    float4 h = float4{acc.x * dn, acc.y * dn, acc.z * dn, acc.w * dn};
    *(ushort4*)&hOut[(long)n * TG_D + fo] = tg71_pack4(h);
    if (writeG) {
        float4 gg = float4{h.x * dn, h.y * dn, h.z * dn, h.w * dn};
        *(ushort4*)&gOut[(long)n * TG_D + fo] = tg71_pack4(gg);
    }
}

// ---- MFMA tiled GEMM: M-tile 128, N=64, K=256 (4 segments of 64) ----
// Fragment layouts (HW-verified, learn_hip m89/m120):
//   A: row = lane&15, k = (lane>>4)*8 + j ; B: col = lane&15, same k
//   D: col = lane&15, row = (lane>>4)*4 + reg
// h0Mode: 0 = follow flags (model input x), 2 = always bf16.
// !doHead: writes yOut (bf16 h) and gOut = dis⊙y (for the next prop chain).
__global__ __launch_bounds__(256) void tg71_gemm(
    const void* h0, int h0Mode, const unsigned short* g1, const unsigned short* g2,
    const unsigned short* g3, const unsigned short* Wt, const void* bias, const int* flags,
    const float* __restrict__ dis, unsigned short* yOut, unsigned short* gOut,
    int doHead, const void* Wc, const void* bc, void* outp) {
    __shared__ __align__(16) unsigned short sA[128 * 72];  // 18.4 KB hop tile (pitch 72)
    __shared__ __align__(16) unsigned short sB[64 * 72];   // 9.2 KB Wt slice (pitch 72)

    const int t    = threadIdx.x;
    const int wave = t >> 6;
    const int lane = t & 63;
    const int quad = lane >> 4;
    const int lr   = lane & 15;
    const int fF   = flags[1];
    const int h0F32 = (h0Mode == 2) ? 0 : fF;
    const long tile = (long)blockIdx.x * 128;

    tg71_f4 acc[2][4];
#pragma unroll
    for (int mt = 0; mt < 2; ++mt)
#pragma unroll
        for (int nt = 0; nt < 4; ++nt) acc[mt][nt] = tg71_f4{0.f, 0.f, 0.f, 0.f};

    for (int seg = 0; seg < 4; ++seg) {
        const int hf = (seg == 0) ? h0F32 : 0;
        const void* hs = (seg == 0) ? h0
                       : (seg == 1 ? (const void*)g1 : (seg == 2 ? (const void*)g2 : (const void*)g3));
        if (seg) __syncthreads();
        for (int c = t; c < 1024; c += 256) {
            int n = c >> 4, k4 = (c & 15) * 4;
            *(ushort4*)&sB[n * 72 + k4] = *(const ushort4*)&Wt[n * 256 + seg * 64 + k4];
        }
        for (int c = t; c < 2048; c += 256) {
            int m = c >> 4, f4 = (c & 15) * 4;
            long n = tile + m;
            ushort4 hv = ushort4{0, 0, 0, 0};
            if (n < TG_NN) {
                if (hf) hv = tg71_pack4(*(const float4*)((const float*)hs + n * TG_D + f4));
                else    hv = *(const ushort4*)((const unsigned short*)hs + n * TG_D + f4);
            }
            *(ushort4*)&sA[m * 72 + f4] = hv;
        }
        __syncthreads();
#pragma unroll
        for (int ks = 0; ks < 2; ++ks) {
            int ko = ks * 32 + quad * 8;
            tg71_s8 a0 = *(const tg71_s8*)&sA[(wave * 32 + lr) * 72 + ko];
            tg71_s8 a1 = *(const tg71_s8*)&sA[(wave * 32 + 16 + lr) * 72 + ko];
            tg71_s8 b0 = *(const tg71_s8*)&sB[(lr) * 72 + ko];
            tg71_s8 b1 = *(const tg71_s8*)&sB[(16 + lr) * 72 + ko];
            tg71_s8 b2 = *(const tg71_s8*)&sB[(32 + lr) * 72 + ko];
            tg71_s8 b3 = *(const tg71_s8*)&sB[(48 + lr) * 72 + ko];
            acc[0][0] = __builtin_amdgcn_mfma_f32_16x16x32_bf16(a0, b0, acc[0][0], 0, 0, 0);
            acc[0][1] = __builtin_amdgcn_mfma_f32_16x16x32_bf16(a0, b1, acc[0][1], 0, 0, 0);
            acc[0][2] = __builtin_amdgcn_mfma_f32_16x16x32_bf16(a0, b2, acc[0][2], 0, 0, 0);
            acc[0][3] = __builtin_amdgcn_mfma_f32_16x16x32_bf16(a0, b3, acc[0][3], 0, 0, 0);
            acc[1][0] = __builtin_amdgcn_mfma_f32_16x16x32_bf16(a1, b0, acc[1][0], 0, 0, 0);
            acc[1][1] = __builtin_amdgcn_mfma_f32_16x16x32_bf16(a1, b1, acc[1][1], 0, 0, 0);
            acc[1][2] = __builtin_amdgcn_mfma_f32_16x16x32_bf16(a1, b2, acc[1][2], 0, 0, 0);
            acc[1][3] = __builtin_amdgcn_mfma_f32_16x16x32_bf16(a1, b3, acc[1][3], 0, 0, 0);
        }
    }

    float bv[4];
#pragma unroll
    for (int nt = 0; nt < 4; ++nt) bv[nt] = tg71_ld(bias, nt * 16 + lr, fF);

    __syncthreads();  // all MFMA LDS reads done before reuse

    const int zp = doHead ? 68 : 64;
#pragma unroll
    for (int mt = 0; mt < 2; ++mt) {
#pragma unroll
        for (int r = 0; r < 4; ++r) {
            int ml = wave * 32 + mt * 16 + quad * 4 + r;
#pragma unroll
            for (int nt = 0; nt < 4; ++nt) {
                float v = fmaxf(acc[mt][nt][r] + bv[nt], 0.f);
                sA[ml * zp + nt * 16 + lr] = tg71_f2b(v);
            }
        }
    }

    if (!doHead) {
        __syncthreads();
        for (int c = t; c < 2048; c += 256) {
            int m = c >> 4, f4 = (c & 15) * 4;
            long n = tile + m;
            if (n < TG_NN) {
                ushort4 hv = *(const ushort4*)&sA[m * 64 + f4];
                *(ushort4*)&yOut[n * TG_D + f4] = hv;
                float d = dis[n];
                float4 gv = tg71_u2f4(hv);
                gv.x *= d; gv.y *= d; gv.z *= d; gv.w *= d;
                *(ushort4*)&gOut[n * TG_D + f4] = tg71_pack4(gv);
            }
        }
        return;
    }

    // fused head: z parked in sA (pitch 68); stage Wc^T (bf16) + bc in sB
    for (int i = t; i < 64 * TG_NC; i += 256) {
        int f = i / TG_NC, c = i - f * TG_NC;
        sB[c * 68 + f] = fF ? tg71_f2b(((const float*)Wc)[i]) : ((const unsigned short*)Wc)[i];
    }
    if (t < TG_NC) sB[40 * 68 + t] = fF ? tg71_f2b(((const float*)bc)[t]) : ((const unsigned short*)bc)[t];
    __syncthreads();

    const int jb = t & 7;   // 0..7 -> cols jb*5..jb*5+4
    const int mb = t >> 3;  // 0..31 -> nodes mb + 32*i
    float hacc[4][5];
#pragma unroll
    for (int i = 0; i < 4; ++i)
#pragma unroll
        for (int q = 0; q < 5; ++q) hacc[i][q] = 0.f;
    for (int fc = 0; fc < 64; fc += 4) {
        float4 zv[4], wv[5];
#pragma unroll
        for (int i = 0; i < 4; ++i)
            zv[i] = tg71_u2f4(*(const ushort4*)&sA[(mb + 32 * i) * 68 + fc]);
#pragma unroll
        for (int q = 0; q < 5; ++q)
            wv[q] = tg71_u2f4(*(const ushort4*)&sB[(jb * 5 + q) * 68 + fc]);
#pragma unroll
        for (int i = 0; i < 4; ++i)
#pragma unroll
            for (int q = 0; q < 5; ++q)
                hacc[i][q] += zv[i].x * wv[q].x + zv[i].y * wv[q].y +
                              zv[i].z * wv[q].z + zv[i].w * wv[q].w;
    }
#pragma unroll
    for (int i = 0; i < 4; ++i) {
        long n = tile + mb + 32 * i;
        if (n < TG_NN) {
#pragma unroll
            for (int q = 0; q < 5; ++q) {
                int c = jb * 5 + q;
                tg71_st(outp, n * TG_NC + c, fF, hacc[i][q] + tg71_b2f(sB[40 * 68 + c]));
            }
        }
    }
}

extern "C" void kernel_launch(void* const* d_in, const int* in_sizes, int n_in,
                              void* d_out, int out_size, void* d_ws, size_t ws_size,
                              hipStream_t stream) {
    const void* x  = d_in[0];
    const int*  ei = (const int*)d_in[1];
    const void* W1 = d_in[2];
    const void* b1 = d_in[3];
    const void* W2 = d_in[4];
    const void* b2 = d_in[5];
    const void* Wc = d_in[6];
    const void* bc = d_in[7];

    // workspace layout (4-byte words); hop buffers bf16, base 16B-aligned
    int*   flags  = (int*)d_ws;                     // [16]
    int*   srcI   = flags + 16;                     // [NE]
    int*   dstI   = srcI + TG_NE;                   // [NE]
    int*   srcS   = dstI + TG_NE;                   // [NE]
    int*   cnt    = srcS + TG_NE;                   // [NN]
    float* dis    = (float*)(cnt + TG_NN);          // [NN]
    int*   rowptr = (int*)(dis + TG_NN);            // [NN+1]
    int*   fill   = rowptr + TG_NN + 1;             // [NN]
    int*   part   = fill + TG_NN;                   // [128]
    unsigned short* S1 = (unsigned short*)(((uintptr_t)(part + 128) + 15) & ~(uintptr_t)15);
    unsigned short* S2 = S1 + (long)TG_NN * TG_D;
    unsigned short* S3 = S2 + (long)TG_NN * TG_D;
    unsigned short* S4 = S3 + (long)TG_NN * TG_D;
    unsigned short* S5 = S4 + (long)TG_NN * TG_D;   // Y
    unsigned short* Wt1 = S5 + (long)TG_NN * TG_D;  // [64*256]
    unsigned short* Wt2 = Wt1 + 64 * 256;           // [64*256]

    const int gE  = (TG_NE + TG_BT - 1) / TG_BT;
    const int gN  = (TG_NN + TG_BT - 1) / TG_BT;
    const int gP  = TG_NN / 4 * 64 / TG_BT;         // 6250: 4 nodes/wave
    const int gX  = (TG_NN * TG_D / 4 + TG_BT - 1) / TG_BT;  // gx: 4 elems/thread
    const int gT  = (TG_NN + 127) / 128;            // 782 gemm tiles

    tg71_detect<<<1, 64, 0, stream>>>(ei, (const unsigned short*)W1, flags);
    tg71_wt<<<64, TG_BT, 0, stream>>>(W1, flags, Wt1);
    tg71_wt<<<64, TG_BT, 0, stream>>>(W2, flags, Wt2);

    // CSR build
    tg71_zero_i<<<gN, TG_BT, 0, stream>>>(cnt, TG_NN);
    tg71_edges<<<gE, TG_BT, 0, stream>>>(ei, flags, srcI, dstI, cnt);
    tg71_scan1<<<TG_NP, TG_BT, 0, stream>>>(cnt, rowptr, part, dis);
    tg71_scan2<<<1, 128, 0, stream>>>(part);
    tg71_scan3<<<gN, TG_BT, 0, stream>>>(rowptr, part, fill);
    for (int pass = 0; pass < 4; ++pass)
        tg71_scatter<<<gE, TG_BT, 0, stream>>>(srcI, dstI, fill, srcS, pass);

    // layer 1: g0 = dis⊙x; hops via pre-scaled chain
    tg71_gx<<<gX, TG_BT, 0, stream>>>(x, flags, dis, S1);
    tg71_prop_g<<<gP, TG_BT, 0, stream>>>(rowptr, srcS, dis, S1, S2, S3, 1);  // A_h=S2, A_g=S3
    tg71_prop_g<<<gP, TG_BT, 0, stream>>>(rowptr, srcS, dis, S3, S4, S1, 1);  // B_h=S4, B_g=S1
    tg71_prop_g<<<gP, TG_BT, 0, stream>>>(rowptr, srcS, dis, S1, S3, nullptr, 0);  // C_h=S3
    tg71_gemm<<<gT, TG_BT, 0, stream>>>(x, 0, S2, S4, S3, Wt1, b1, flags,
                                        dis, S5, S1, 0, nullptr, nullptr, nullptr);  // Y=S5, gY=S1

    // layer 2 + fused head
    tg71_prop_g<<<gP, TG_BT, 0, stream>>>(rowptr, srcS, dis, S1, S2, S3, 1);
    tg71_prop_g<<<gP, TG_BT, 0, stream>>>(rowptr, srcS, dis, S3, S4, S1, 1);
    tg71_prop_g<<<gP, TG_BT, 0, stream>>>(rowptr, srcS, dis, S1, S3, nullptr, 0);
    tg71_gemm<<<gT, TG_BT, 0, stream>>>(S5, 2, S2, S4, S3, Wt2, b2, flags,
                                        dis, nullptr, nullptr, 1, Wc, bc, d_out);
}

// Round 12
// 539.349 us; speedup vs baseline: 9.2516x; 1.0440x over previous
//
#include <hip/hip_runtime.h>
#include <hip/hip_bf16.h>
#include <stdint.h>

static constexpr int TG_NN = 100000;
static constexpr int TG_NE = 1200000;
static constexpr int TG_D  = 64;
static constexpr int TG_NC = 40;
static constexpr int TG_BT = 256;
static constexpr int TG_NP = (TG_NN + 1023) / 1024;  // scan blocks (98)
static constexpr int TG_GN = (TG_NN + TG_BT - 1) / TG_BT;  // 391

typedef __attribute__((ext_vector_type(8))) short tg71_s8;
typedef __attribute__((ext_vector_type(4))) float tg71_f4;

// ---- dtype helpers ----
__device__ __forceinline__ float tg71_b2f(unsigned short u) {
    return __uint_as_float(((unsigned int)u) << 16);
}
__device__ __forceinline__ unsigned short tg71_f2b(float v) {
    __hip_bfloat16 b = __float2bfloat16(v);  // RNE
    return __builtin_bit_cast(unsigned short, b);
}
__device__ __forceinline__ float tg71_ld(const void* p, long i, int isF32) {
    if (isF32) return ((const float*)p)[i];
    return tg71_b2f(((const unsigned short*)p)[i]);
}
__device__ __forceinline__ void tg71_st(void* p, long i, int isF32, float v) {
    if (isF32) ((float*)p)[i] = v;
    else ((unsigned short*)p)[i] = tg71_f2b(v);
}
__device__ __forceinline__ float4 tg71_u2f4(ushort4 u) {
    return float4{tg71_b2f(u.x), tg71_b2f(u.y), tg71_b2f(u.z), tg71_b2f(u.w)};
}
__device__ __forceinline__ float4 tg71_ld4(const void* p, long i, int isF32) {
    if (isF32) return *(const float4*)((const float*)p + i);
    return tg71_u2f4(*(const ushort4*)((const unsigned short*)p + i));
}
__device__ __forceinline__ ushort4 tg71_pack4(float4 v) {
    return ushort4{tg71_f2b(v.x), tg71_f2b(v.y), tg71_f2b(v.z), tg71_f2b(v.w)};
}

// flags[0] = edge_index is int64 ; flags[1] = float tensors are fp32
__global__ void tg71_detect(const int* ei, const unsigned short* w1bits, int* flags) {
    int lane = threadIdx.x;  // 64 threads
    int hi = ei[2 * lane + 1];
    unsigned long long bi = __ballot(hi != 0);
    float mx = 0.0f;
    for (int k = lane; k < 2048; k += 64) {
        float v = fabsf(tg71_b2f(w1bits[k]));
        if (!(v == v)) v = 1e30f;
        mx = fmaxf(mx, v);
    }
    unsigned long long bf = __ballot(mx > 1e4f);
    if (lane == 0) { flags[0] = (bi == 0ULL) ? 1 : 0; flags[1] = (bf != 0ULL) ? 1 : 0; }
}

// Kept for pipeline symbol validation; not launched (head writes all outputs).
extern "C" __global__ void TAGModel_71227737636876_kernel(void* out, const int* flags) {
    long i = (long)blockIdx.x * blockDim.x + threadIdx.x;
    if (i < (long)TG_NN * TG_NC) tg71_st(out, i, flags[1], 123.0f);
}

// prep: blocks 0..63 -> Wt1 transpose; 64..127 -> Wt2; 128.. -> zero cnt
__global__ void tg71_prep(const void* W1, const void* W2, const int* flags,
                          unsigned short* Wt1, unsigned short* Wt2, int* cnt) {
    int b = blockIdx.x;
    if (b < 128) {
        const void* W = (b < 64) ? W1 : W2;
        unsigned short* Wt = (b < 64) ? Wt1 : Wt2;
        int i = (b & 63) * TG_BT + threadIdx.x;  // 0..16383
        int k = i >> 6, n = i & 63;
        Wt[n * 256 + k] = flags[1] ? tg71_f2b(((const float*)W)[i]) : ((const unsigned short*)W)[i];
    } else {
        int i = (b - 128) * TG_BT + threadIdx.x;
        if (i < TG_NN) cnt[i] = 0;
    }
}

// edge decode + degree histogram fused (cnt zeroed by prep)
__global__ void tg71_edges(const int* ei, const int* flags, int* srcI, int* dstI, int* cnt) {
    int e = blockIdx.x * blockDim.x + threadIdx.x;
    if (e >= TG_NE) return;
    int s, d;
    if (flags[0]) { s = ei[2 * e]; d = ei[2 * TG_NE + 2 * e]; }
    else          { s = ei[e];     d = ei[TG_NE + e]; }
    srcI[e] = s;
    dstI[e] = d;
    atomicAdd(cnt + d, 1);
}

// ---- exclusive scan of cnt -> rowptr; also emits dis = deg^-1/2 and sq = deg^1/2 ----
__global__ void tg71_scan1(const int* cnt, int* rowptr, int* part, float* dis, float* sq) {
    __shared__ int sh[256];
    int t = threadIdx.x;
    int base = blockIdx.x * 1024 + t * 4;
    int v0 = base + 0 < TG_NN ? cnt[base + 0] : 0;
    int v1 = base + 1 < TG_NN ? cnt[base + 1] : 0;
    int v2 = base + 2 < TG_NN ? cnt[base + 2] : 0;
    int v3 = base + 3 < TG_NN ? cnt[base + 3] : 0;
    if (base + 0 < TG_NN) { dis[base + 0] = v0 > 0 ? rsqrtf((float)v0) : 0.f; sq[base + 0] = v0 > 0 ? sqrtf((float)v0) : 0.f; }
    if (base + 1 < TG_NN) { dis[base + 1] = v1 > 0 ? rsqrtf((float)v1) : 0.f; sq[base + 1] = v1 > 0 ? sqrtf((float)v1) : 0.f; }
    if (base + 2 < TG_NN) { dis[base + 2] = v2 > 0 ? rsqrtf((float)v2) : 0.f; sq[base + 2] = v2 > 0 ? sqrtf((float)v2) : 0.f; }
    if (base + 3 < TG_NN) { dis[base + 3] = v3 > 0 ? rsqrtf((float)v3) : 0.f; sq[base + 3] = v3 > 0 ? sqrtf((float)v3) : 0.f; }
    int p1 = v0, p2 = v0 + v1, p3 = v0 + v1 + v2, sum = p3 + v3;
    sh[t] = sum;
    __syncthreads();
    for (int off = 1; off < 256; off <<= 1) {
        int x = (t >= off) ? sh[t - off] : 0;
        __syncthreads();
        if (t >= off) sh[t] += x;
        __syncthreads();
    }
    int ex = sh[t] - sum;
    if (base + 0 < TG_NN) rowptr[base + 0] = ex;
    if (base + 1 < TG_NN) rowptr[base + 1] = ex + p1;
    if (base + 2 < TG_NN) rowptr[base + 2] = ex + p2;
    if (base + 3 < TG_NN) rowptr[base + 3] = ex + p3;
    if (t == 255) part[blockIdx.x] = sh[255];
}

__global__ void tg71_scan2(int* part) {
    __shared__ int sh[128];
    int t = threadIdx.x;
    int v = t < TG_NP ? part[t] : 0;
    sh[t] = v;
    __syncthreads();
    for (int off = 1; off < 128; off <<= 1) {
        int x = (t >= off) ? sh[t - off] : 0;
        __syncthreads();
        if (t >= off) sh[t] += x;
        __syncthreads();
    }
    if (t < TG_NP) part[t] = sh[t] - v;
}

__global__ void tg71_scan3(int* rowptr, const int* part, int* fill) {
    int i = blockIdx.x * blockDim.x + threadIdx.x;
    if (i < TG_NN) {
        int r = rowptr[i] + part[i >> 10];
        rowptr[i] = r;
        fill[i] = r;
    }
    if (i == 0) rowptr[TG_NN] = TG_NE;
}

// Windowed CSR scatter: pass p handles dst in [p*32768, (p+1)*32768).
__global__ void tg71_scatter(const int* __restrict__ srcI, const int* __restrict__ dstI,
                             int* fill, int* srcS, int pass) {
    int e = blockIdx.x * blockDim.x + threadIdx.x;
    if (e >= TG_NE) return;
    int d = dstI[e];
    if ((d >> 15) != pass) return;
    int pos = atomicAdd(fill + d, 1);
    srcS[pos] = srcI[e];
}

// g0 = dis ⊙ x  (bf16 out; x fp32 or bf16 per flags)
__global__ void tg71_gx(const void* x, const int* flags, const float* __restrict__ dis,
                        unsigned short* __restrict__ g) {
    int tid = blockIdx.x * blockDim.x + threadIdx.x;
    long i4 = (long)tid * 4;
    if (i4 >= (long)TG_NN * TG_D) return;
    int n = (int)(i4 >> 6);
    float d = dis[n];
    float4 v = tg71_ld4(x, i4, flags[1]);
    v.x *= d; v.y *= d; v.z *= d; v.w *= d;
    *(ushort4*)&g[i4] = tg71_pack4(v);
}

// ---- propagation on pre-scaled hops: g'[n] = dis[n]^2 * Σ g[s] (g-only output) ----
__global__ void tg71_prop_g(const int* __restrict__ rowptr, const int* __restrict__ srcS,
                            const float* __restrict__ dis, const unsigned short* __restrict__ g,
                            unsigned short* __restrict__ gOut) {
    int gid = blockIdx.x * blockDim.x + threadIdx.x;
    int wid = gid >> 6, lane = gid & 63;
    int grp = lane >> 4, li = lane & 15;
    int n = wid * 4 + grp;
    int r0 = rowptr[n], r1 = rowptr[n + 1];
    float4 acc = float4{0.f, 0.f, 0.f, 0.f};
    long fo = (long)li * 4;
    int k = r0;
    for (; k + 8 <= r1; k += 8) {
        int s0 = srcS[k],     s1 = srcS[k + 1], s2 = srcS[k + 2], s3 = srcS[k + 3];
        int s4 = srcS[k + 4], s5 = srcS[k + 5], s6 = srcS[k + 6], s7 = srcS[k + 7];
        float4 a0 = tg71_u2f4(*(const ushort4*)&g[(long)s0 * TG_D + fo]);
        float4 a1 = tg71_u2f4(*(const ushort4*)&g[(long)s1 * TG_D + fo]);
        float4 a2 = tg71_u2f4(*(const ushort4*)&g[(long)s2 * TG_D + fo]);
        float4 a3 = tg71_u2f4(*(const ushort4*)&g[(long)s3 * TG_D + fo]);
        float4 a4 = tg71_u2f4(*(const ushort4*)&g[(long)s4 * TG_D + fo]);
        float4 a5 = tg71_u2f4(*(const ushort4*)&g[(long)s5 * TG_D + fo]);
        float4 a6 = tg71_u2f4(*(const ushort4*)&g[(long)s6 * TG_D + fo]);
        float4 a7 = tg71_u2f4(*(const ushort4*)&g[(long)s7 * TG_D + fo]);
        acc.x += ((a0.x + a1.x) + (a2.x + a3.x)) + ((a4.x + a5.x) + (a6.x + a7.x));
        acc.y += ((a0.y + a1.y) + (a2.y + a3.y)) + ((a4.y + a5.y) + (a6.y + a7.y));
        acc.z += ((a0.z + a1.z) + (a2.z + a3.z)) + ((a4.z + a5.z) + (a6.z + a7.z));
        acc.w += ((a0.w + a1.w) + (a2.w + a3.w)) + ((a4.w + a5.w) + (a6.w + a7.w));
    }
    for (; k + 4 <= r1; k += 4) {
        int s0 = srcS[k], s1 = srcS[k + 1], s2 = srcS[k + 2], s3 = srcS[k + 3];
        float4 a0 = tg71_u2f4(*(const ushort4*)&g[(long)s0 * TG_D + fo]);
        float4 a1 = tg71_u2f4(*(const ushort4*)&g[(long)s1 * TG_D + fo]);
        float4 a2 = tg71_u2f4(*(const ushort4*)&g[(long)s2 * TG_D + fo]);
        float4 a3 = tg71_u2f4(*(const ushort4*)&g[(long)s3 * TG_D + fo]);
        acc.x += (a0.x + a1.x) + (a2.x + a3.x);
        acc.y += (a0.y + a1.y) + (a2.y + a3.y);
        acc.z += (a0.z + a1.z) + (a2.z + a3.z);
        acc.w += (a0.w + a1.w) + (a2.w + a3.w);
    }
    for (; k < r1; ++k) {
        int s = srcS[k];
        float4 a = tg71_u2f4(*(const ushort4*)&g[(long)s * TG_D + fo]);
        acc.x += a.x; acc.y += a.y; acc.z += a.z; acc.w += a.w;
    }
    float dn = dis[n];
    float d2 = dn * dn;
    acc.x *= d2; acc.y *= d2; acc.z *= d2; acc.w *= d2;
    *(ushort4*)&gOut[(long)n * TG_D + fo] = tg71_pack4(acc);
}

// ---- A-fragment load, direct from global (layout: row=lane&15, k=quad*8+j) ----
__device__ __forceinline__ tg71_s8 tg71_afrag(const void* h, int isF32, long row, int ko,
                                              bool valid, int scaled, float s) {
    tg71_s8 r;
    if (!valid) {
#pragma unroll
        for (int i = 0; i < 8; ++i) r[i] = 0;
        return r;
    }
    if (isF32) {
        const float* p = (const float*)h + row * TG_D + ko;
        float4 u = *(const float4*)p;
        float4 v = *(const float4*)(p + 4);
        if (scaled) { u.x *= s; u.y *= s; u.z *= s; u.w *= s; v.x *= s; v.y *= s; v.z *= s; v.w *= s; }
        r[0] = (short)tg71_f2b(u.x); r[1] = (short)tg71_f2b(u.y);
        r[2] = (short)tg71_f2b(u.z); r[3] = (short)tg71_f2b(u.w);
        r[4] = (short)tg71_f2b(v.x); r[5] = (short)tg71_f2b(v.y);
        r[6] = (short)tg71_f2b(v.z); r[7] = (short)tg71_f2b(v.w);
        return r;
    }
    tg71_s8 raw = *(const tg71_s8*)((const unsigned short*)h + row * TG_D + ko);
    if (!scaled) return raw;
#pragma unroll
    for (int i = 0; i < 8; ++i)
        r[i] = (short)tg71_f2b(tg71_b2f((unsigned short)raw[i]) * s);
    return r;
}

// ---- MFMA GEMM, zero-staging: M-tile 128 (4 waves x 32 rows), N=64, K=256 ----
// A-frags and B-frags loaded directly from global (no LDS in the K-loop, no barriers).
// h0Mode: 0 = follow flags (x), 2 = bf16. scale0: seg0 rows scaled by sq (gY path).
// Segments 1-3 (g1..g3) are always bf16 + scaled by sq.
// !doHead: writes gOut = dis ⊙ relu(..) only. doHead: classifier head fused.
__global__ __launch_bounds__(256) void tg71_gemm(
    const void* h0, int h0Mode, int scale0, const unsigned short* g1, const unsigned short* g2,
    const unsigned short* g3, const unsigned short* Wt, const void* bias, const int* flags,
    const float* __restrict__ dis, const float* __restrict__ sq,
    unsigned short* gOut, int doHead, const void* Wc, const void* bc, void* outp) {
    __shared__ __align__(16) unsigned short sZ[128 * 68];  // 17.4 KB z/y park
    __shared__ unsigned short sWc[41 * 68];                // 5.6 KB head weights

    const int t    = threadIdx.x;
    const int wave = t >> 6;
    const int lane = t & 63;
    const int quad = lane >> 4;
    const int lr   = lane & 15;
    const int fF   = flags[1];
    const int h0F32 = (h0Mode == 2) ? 0 : fF;
    const long tile = (long)blockIdx.x * 128;
    const long row0 = tile + wave * 32 + lr;
    const long row1 = row0 + 16;
    const bool v0 = row0 < TG_NN, v1 = row1 < TG_NN;
    const float s0 = v0 ? sq[row0] : 0.f;
    const float s1 = v1 ? sq[row1] : 0.f;

    tg71_f4 acc[2][4];
#pragma unroll
    for (int mt = 0; mt < 2; ++mt)
#pragma unroll
        for (int nt = 0; nt < 4; ++nt) acc[mt][nt] = tg71_f4{0.f, 0.f, 0.f, 0.f};

#pragma unroll
    for (int seg = 0; seg < 4; ++seg) {
        const void* hs = (seg == 0) ? h0
                       : (seg == 1 ? (const void*)g1 : (seg == 2 ? (const void*)g2 : (const void*)g3));
        const int hf = (seg == 0) ? h0F32 : 0;
        const int sc = (seg == 0) ? scale0 : 1;
#pragma unroll
        for (int ks = 0; ks < 2; ++ks) {
            const int ko = ks * 32 + quad * 8;
            tg71_s8 a0 = tg71_afrag(hs, hf, row0, ko, v0, sc, s0);
            tg71_s8 a1 = tg71_afrag(hs, hf, row1, ko, v1, sc, s1);
            const int kw = seg * 64 + ko;
            tg71_s8 b0 = *(const tg71_s8*)&Wt[(0  + lr) * 256 + kw];
            tg71_s8 b1 = *(const tg71_s8*)&Wt[(16 + lr) * 256 + kw];
            tg71_s8 b2 = *(const tg71_s8*)&Wt[(32 + lr) * 256 + kw];
            tg71_s8 b3 = *(const tg71_s8*)&Wt[(48 + lr) * 256 + kw];
            acc[0][0] = __builtin_amdgcn_mfma_f32_16x16x32_bf16(a0, b0, acc[0][0], 0, 0, 0);
            acc[0][1] = __builtin_amdgcn_mfma_f32_16x16x32_bf16(a0, b1, acc[0][1], 0, 0, 0);
            acc[0][2] = __builtin_amdgcn_mfma_f32_16x16x32_bf16(a0, b2, acc[0][2], 0, 0, 0);
            acc[0][3] = __builtin_amdgcn_mfma_f32_16x16x32_bf16(a0, b3, acc[0][3], 0, 0, 0);
            acc[1][0] = __builtin_amdgcn_mfma_f32_16x16x32_bf16(a1, b0, acc[1][0], 0, 0, 0);
            acc[1][1] = __builtin_amdgcn_mfma_f32_16x16x32_bf16(a1, b1, acc[1][1], 0, 0, 0);
            acc[1][2] = __builtin_amdgcn_mfma_f32_16x16x32_bf16(a1, b2, acc[1][2], 0, 0, 0);
            acc[1][3] = __builtin_amdgcn_mfma_f32_16x16x32_bf16(a1, b3, acc[1][3], 0, 0, 0);
        }
    }

    // epilogue: bias + relu, park bf16 in sZ (D layout: col=lane&15, row=quad*4+reg)
    float bv[4];
#pragma unroll
    for (int nt = 0; nt < 4; ++nt) bv[nt] = tg71_ld(bias, nt * 16 + lr, fF);
#pragma unroll
    for (int mt = 0; mt < 2; ++mt) {
#pragma unroll
        for (int r = 0; r < 4; ++r) {
            int ml = wave * 32 + mt * 16 + quad * 4 + r;
#pragma unroll
            for (int nt = 0; nt < 4; ++nt) {
                float v = fmaxf(acc[mt][nt][r] + bv[nt], 0.f);
                sZ[ml * 68 + nt * 16 + lr] = tg71_f2b(v);
            }
        }
    }

    if (!doHead) {
        __syncthreads();
        for (int c = t; c < 2048; c += 256) {
            int m = c >> 4, f4 = (c & 15) * 4;
            long n = tile + m;
            if (n < TG_NN) {
                float d = dis[n];
                float4 gv = tg71_u2f4(*(const ushort4*)&sZ[m * 68 + f4]);
                gv.x *= d; gv.y *= d; gv.z *= d; gv.w *= d;
                *(ushort4*)&gOut[n * TG_D + f4] = tg71_pack4(gv);
            }
        }
        return;
    }

    // fused head: stage Wc^T (bf16) + bc in sWc
    for (int i = t; i < 64 * TG_NC; i += 256) {
        int f = i / TG_NC, c = i - f * TG_NC;
        sWc[c * 68 + f] = fF ? tg71_f2b(((const float*)Wc)[i]) : ((const unsigned short*)Wc)[i];
    }
    if (t < TG_NC) sWc[40 * 68 + t] = fF ? tg71_f2b(((const float*)bc)[t]) : ((const unsigned short*)bc)[t];
    __syncthreads();

    const int jb = t & 7;   // 0..7 -> cols jb*5..jb*5+4
    const int mb = t >> 3;  // 0..31 -> nodes mb + 32*i
    float hacc[4][5];
#pragma unroll
    for (int i = 0; i < 4; ++i)
#pragma unroll
        for (int q = 0; q < 5; ++q) hacc[i][q] = 0.f;
    for (int fc = 0; fc < 64; fc += 4) {
        float4 zv[4], wv[5];
#pragma unroll
        for (int i = 0; i < 4; ++i)
            zv[i] = tg71_u2f4(*(const ushort4*)&sZ[(mb + 32 * i) * 68 + fc]);
#pragma unroll
        for (int q = 0; q < 5; ++q)
            wv[q] = tg71_u2f4(*(const ushort4*)&sWc[(jb * 5 + q) * 68 + fc]);
#pragma unroll
        for (int i = 0; i < 4; ++i)
#pragma unroll
            for (int q = 0; q < 5; ++q)
                hacc[i][q] += zv[i].x * wv[q].x + zv[i].y * wv[q].y +
                              zv[i].z * wv[q].z + zv[i].w * wv[q].w;
    }
#pragma unroll
    for (int i = 0; i < 4; ++i) {
        long n = tile + mb + 32 * i;
        if (n < TG_NN) {
#pragma unroll
            for (int q = 0; q < 5; ++q) {
                int c = jb * 5 + q;
                tg71_st(outp, n * TG_NC + c, fF, hacc[i][q] + tg71_b2f(sWc[40 * 68 + c]));
            }
        }
    }
}

extern "C" void kernel_launch(void* const* d_in, const int* in_sizes, int n_in,
                              void* d_out, int out_size, void* d_ws, size_t ws_size,
                              hipStream_t stream) {
    const void* x  = d_in[0];
    const int*  ei = (const int*)d_in[1];
    const void* W1 = d_in[2];
    const void* b1 = d_in[3];
    const void* W2 = d_in[4];
    const void* b2 = d_in[5];
    const void* Wc = d_in[6];
    const void* bc = d_in[7];

    // workspace layout (4-byte words); hop buffers bf16, base 16B-aligned
    int*   flags  = (int*)d_ws;                     // [16]
    int*   srcI   = flags + 16;                     // [NE]
    int*   dstI   = srcI + TG_NE;                   // [NE]
    int*   srcS   = dstI + TG_NE;                   // [NE]
    int*   cnt    = srcS + TG_NE;                   // [NN]
    float* dis    = (float*)(cnt + TG_NN);          // [NN]
    float* sq     = dis + TG_NN;                    // [NN]
    int*   rowptr = (int*)(sq + TG_NN);             // [NN+1]
    int*   fill   = rowptr + TG_NN + 1;             // [NN]
    int*   part   = fill + TG_NN;                   // [128]
    unsigned short* S1 = (unsigned short*)(((uintptr_t)(part + 128) + 15) & ~(uintptr_t)15);
    unsigned short* S2 = S1 + (long)TG_NN * TG_D;
    unsigned short* S3 = S2 + (long)TG_NN * TG_D;
    unsigned short* S4 = S3 + (long)TG_NN * TG_D;
    unsigned short* Wt1 = S4 + (long)TG_NN * TG_D;  // [64*256]
    unsigned short* Wt2 = Wt1 + 64 * 256;           // [64*256]

    const int gE  = (TG_NE + TG_BT - 1) / TG_BT;
    const int gN  = TG_GN;
    const int gP  = TG_NN / 4 * 64 / TG_BT;         // 6250: 4 nodes/wave
    const int gX  = (TG_NN * TG_D / 4 + TG_BT - 1) / TG_BT;
    const int gT  = (TG_NN + 127) / 128;            // 782 gemm tiles

    tg71_detect<<<1, 64, 0, stream>>>(ei, (const unsigned short*)W1, flags);
    tg71_prep<<<128 + gN, TG_BT, 0, stream>>>(W1, W2, flags, Wt1, Wt2, cnt);

    // CSR build
    tg71_edges<<<gE, TG_BT, 0, stream>>>(ei, flags, srcI, dstI, cnt);
    tg71_scan1<<<TG_NP, TG_BT, 0, stream>>>(cnt, rowptr, part, dis, sq);
    tg71_scan2<<<1, 128, 0, stream>>>(part);
    tg71_scan3<<<gN, TG_BT, 0, stream>>>(rowptr, part, fill);
    for (int pass = 0; pass < 4; ++pass)
        tg71_scatter<<<gE, TG_BT, 0, stream>>>(srcI, dstI, fill, srcS, pass);

    // layer 1: g0 = dis⊙x; g-chain props; gemm reads x raw + g1..g3 (rescaled by sq)
    tg71_gx<<<gX, TG_BT, 0, stream>>>(x, flags, dis, S1);
    tg71_prop_g<<<gP, TG_BT, 0, stream>>>(rowptr, srcS, dis, S1, S2);
    tg71_prop_g<<<gP, TG_BT, 0, stream>>>(rowptr, srcS, dis, S2, S3);
    tg71_prop_g<<<gP, TG_BT, 0, stream>>>(rowptr, srcS, dis, S3, S4);
    tg71_gemm<<<gT, TG_BT, 0, stream>>>(x, 0, 0, S2, S3, S4, Wt1, b1, flags,
                                        dis, sq, S1, 0, nullptr, nullptr, nullptr);  // S1 = gY

    // layer 2 + fused head: seg0 = gY (scaled), g-chain again
    tg71_prop_g<<<gP, TG_BT, 0, stream>>>(rowptr, srcS, dis, S1, S2);
    tg71_prop_g<<<gP, TG_BT, 0, stream>>>(rowptr, srcS, dis, S2, S3);
    tg71_prop_g<<<gP, TG_BT, 0, stream>>>(rowptr, srcS, dis, S3, S4);
    tg71_gemm<<<gT, TG_BT, 0, stream>>>(S1, 2, 1, S2, S3, S4, Wt2, b2, flags,
                                        dis, sq, nullptr, 1, Wc, bc, d_out);
}